// Round 14
// baseline (203.022 us; speedup 1.0000x reference)
//
#include <hip/hip_runtime.h>

typedef unsigned short u16;
typedef unsigned int u32;
typedef __attribute__((ext_vector_type(8))) short bf16x8;
typedef __attribute__((ext_vector_type(4))) float f32x4;

#define LSEQ 1024
#define NSL 16  // k-slices for gemm2 / parts

__device__ __forceinline__ float b2f(u16 v) { return __uint_as_float(((u32)v) << 16); }
__device__ __forceinline__ u16 f2b(float f) {
    u32 x = __float_as_uint(f);
    return (u16)((x + 0x7fffu + ((x >> 16) & 1u)) >> 16);
}
__device__ __forceinline__ float rdf(const void* p, size_t i, int f) {
    return f ? b2f(((const u16*)p)[i]) : ((const float*)p)[i];
}
__device__ __forceinline__ float fsig(float x) {
    return __builtin_amdgcn_rcpf(1.f + __expf(-x));
}

typedef const __attribute__((address_space(1))) u32* gp_t;
typedef __attribute__((address_space(3))) u32* lp_t;
__device__ __forceinline__ void gload16(const u16* g, u16* lds_wave_base) {
    __builtin_amdgcn_global_load_lds((gp_t)g, (lp_t)lds_wave_base, 16, 0, 0);
}

// shared transpose-tile body: dst[Cp,R] = src[R,Cn]^T (zero-padded cols >= Cn)
__device__ __forceinline__ void transpose_tile(const void* src, u16* dst, int R, int Cn,
                                               int br, int bc, int f, u16 (*tile)[36]) {
    int r0 = br * 32, c0 = bc * 32;
    {
        int ty = threadIdx.x >> 3, tx4 = (threadIdx.x & 7) << 2;
        u16 o0 = 0, o1 = 0, o2 = 0, o3 = 0;
        if (c0 + tx4 < Cn) {
            size_t off = (size_t)(r0 + ty) * Cn + c0 + tx4;
            if (f) {
                ushort4 u = *(const ushort4*)((const u16*)src + off);
                o0 = u.x; o1 = u.y; o2 = u.z; o3 = u.w;
            } else {
                float4 v = *(const float4*)((const float*)src + off);
                o0 = f2b(v.x); o1 = f2b(v.y); o2 = f2b(v.z); o3 = f2b(v.w);
            }
        }
        *(ushort4*)(&tile[ty][tx4]) = make_ushort4(o0, o1, o2, o3);
    }
    __syncthreads();
    {
        int cc = threadIdx.x >> 3, r4 = (threadIdx.x & 7) << 2;
        ushort4 o = make_ushort4(tile[r4][cc], tile[r4 + 1][cc], tile[r4 + 2][cc], tile[r4 + 3][cc]);
        *(ushort4*)(dst + (size_t)(c0 + cc) * R + r0 + r4) = o;
    }
}

// ---------------- prep: dtype detect + x->bf16 + W_in^T ONLY (other transposes ride gemm1) ----
__global__ __launch_bounds__(256) void prep_k(const void* __restrict__ x,
                                              const void* __restrict__ W_in,
                                              u16* __restrict__ xb,
                                              u16* __restrict__ W_in_t,
                                              int* __restrict__ flag) {
    __shared__ int cnt;
    __shared__ __align__(8) u16 tile[32][36];
    if (threadIdx.x == 0) cnt = 0;
    __syncthreads();
    const u16* xu = (const u16*)x;
    int c = 0;
#pragma unroll
    for (int j = 0; j < 8; ++j) {
        u16 u = xu[threadIdx.x * 8 + j];
        int e = (u >> 7) & 0xFF;
        c += (e == 0 || (e >= 100 && e <= 140)) ? 1 : 0;
    }
    atomicAdd(&cnt, c);
    __syncthreads();
    const int f = (cnt >= 1638) ? 1 : 0;
    if (blockIdx.x == 0 && threadIdx.x == 0) *flag = f;

    int blk = blockIdx.x;
    if (blk < 1024) {  // x -> bf16, 4 elems/thread
        int i = (blk * 256 + threadIdx.x) * 4;
        ushort4 o;
        if (f) {
            o = *(const ushort4*)(xu + i);
        } else {
            float4 v = *(const float4*)((const float*)x + i);
            o = make_ushort4(f2b(v.x), f2b(v.y), f2b(v.z), f2b(v.w));
        }
        *(ushort4*)(xb + i) = o;
        return;
    }
    blk -= 1024;   // 0..4095: W_in [1024,4096] -> W_in_t, nbc=128
    transpose_tile(W_in, W_in_t, 1024, 4096, blk / 128, blk % 128, f, tile);
}

// ---------------- gemm1 FAT: xz = xb @ W_in_t^T  +  rider blocks do W_out/W_x/W_dt transposes --
// grid (16, 32+152): blockIdx.y < 32 -> 64x128 gemm tile; else rider id in [0,2432).
__global__ __launch_bounds__(256) void gemm1_fat_k(const u16* __restrict__ A,
                                                   const u16* __restrict__ Bt,
                                                   u16* __restrict__ C,
                                                   const void* __restrict__ W_out,
                                                   const void* __restrict__ W_x,
                                                   const void* __restrict__ W_dt,
                                                   u16* __restrict__ W_out_t,
                                                   u16* __restrict__ W_x_t,
                                                   u16* __restrict__ W_dt_t,
                                                   const int* __restrict__ flag) {
    constexpr int MT = 2, NT = 4, BM = 64, BN = 128, N = 4096, K = 1024;
    __shared__ __align__(16) u16 As[2][2 * BM * 32];
    __shared__ __align__(16) u16 Bs[2][2 * BN * 32];
    __shared__ __align__(8) u16 tile[32][36];
    if (blockIdx.y >= 32) {  // ---- transpose rider ----
        int id = (blockIdx.y - 32) * 16 + blockIdx.x;  // 0..2431
        const int f = flag[0];
        const void* src; u16* dst; int R, Cn, nbc, t;
        if (id < 2048)      { src = W_out; dst = W_out_t; R = 2048; Cn = 1024; nbc = 32; t = id; }
        else if (id < 2304) { src = W_x;   dst = W_x_t;   R = 2048; Cn = 96;   nbc = 4;  t = id - 2048; }
        else                { src = W_dt;  dst = W_dt_t;  R = 64;   Cn = 2048; nbc = 64; t = id - 2304; }
        transpose_tile(src, dst, R, Cn, t / nbc, t % nbc, f, tile);
        return;
    }
    const int tid = threadIdx.x;
    const int w = tid >> 6, lane = tid & 63;
    const int wm = w & 1, wn = w >> 1;
    const int m_blk = blockIdx.x * BM, n_blk = blockIdx.y * BN;
    const int lm = lane & 15, lq = lane >> 4;
    const int sr = lane >> 2, sc = (lane & 3) << 3;

    f32x4 acc[MT][NT];
#pragma unroll
    for (int i = 0; i < MT; ++i)
#pragma unroll
        for (int j = 0; j < NT; ++j) acc[i][j] = (f32x4){0.f, 0.f, 0.f, 0.f};

    auto stage = [&](int buf, int kb) {
#pragma unroll
        for (int cch = 0; cch < 2; ++cch) {
#pragma unroll
            for (int i = 0; i < BM / 64; ++i) {
                int row = i * 64 + w * 16;
                gload16(A + (size_t)(m_blk + row + sr) * K + kb + cch * 32 + sc,
                        &As[buf][cch * BM * 32 + row * 32]);
            }
#pragma unroll
            for (int i = 0; i < BN / 64; ++i) {
                int row = i * 64 + w * 16;
                gload16(Bt + (size_t)(n_blk + row + sr) * K + kb + cch * 32 + sc,
                        &Bs[buf][cch * BN * 32 + row * 32]);
            }
        }
    };
    auto compute = [&](int buf) {
#pragma unroll
        for (int cch = 0; cch < 2; ++cch) {
            bf16x8 af[MT], bf[NT];
#pragma unroll
            for (int tm = 0; tm < MT; ++tm)
                af[tm] = *(const bf16x8*)(&As[buf][cch * BM * 32 +
                                                   (wm * 16 * MT + tm * 16 + lm) * 32 + lq * 8]);
#pragma unroll
            for (int tn = 0; tn < NT; ++tn)
                bf[tn] = *(const bf16x8*)(&Bs[buf][cch * BN * 32 +
                                                   (wn * 16 * NT + tn * 16 + lm) * 32 + lq * 8]);
#pragma unroll
            for (int tm = 0; tm < MT; ++tm)
#pragma unroll
                for (int tn = 0; tn < NT; ++tn)
                    acc[tm][tn] = __builtin_amdgcn_mfma_f32_16x16x32_bf16(af[tm], bf[tn],
                                                                          acc[tm][tn], 0, 0, 0);
        }
    };

    stage(0, 0);
    __syncthreads();
    int cur = 0;
    for (int kb = 64; kb < K; kb += 64) {
        stage(cur ^ 1, kb);
        compute(cur);
        __syncthreads();
        cur ^= 1;
    }
    compute(cur);

#pragma unroll
    for (int tm = 0; tm < MT; ++tm)
#pragma unroll
        for (int tn = 0; tn < NT; ++tn)
#pragma unroll
            for (int r = 0; r < 4; ++r) {
                int row = m_blk + wm * 16 * MT + tm * 16 + lq * 4 + r;
                int col = n_blk + wn * 16 * NT + tn * 16 + lm;
                C[(size_t)row * N + col] = f2b(acc[tm][tn][r]);
            }
}

// ---------------- GEMM, B transposed (gemm4): C[M,N] = A[M,K] * Bt[N,K]^T ----------------
// BK=64 dbuf. Supports BM=32 (MT=1): stage guards row<BM (waves 2,3 skip A-load).
// <1,2> grid (32,16) = 512 blocks = 2/CU per R8 lesson.
template <int MT, int NT, int OUT_MODE>
__global__ __launch_bounds__(256) void gemm_bt(const u16* __restrict__ A,
                                               const u16* __restrict__ Bt,
                                               void* __restrict__ C,
                                               int M, int N, int K,
                                               const int* __restrict__ flag) {
    constexpr int BM = 32 * MT, BN = 32 * NT;
    __shared__ __align__(16) u16 As[2][2 * BM * 32];
    __shared__ __align__(16) u16 Bs[2][2 * BN * 32];
    const int tid = threadIdx.x;
    const int w = tid >> 6, lane = tid & 63;
    const int wm = w & 1, wn = w >> 1;
    const int m_blk = blockIdx.x * BM, n_blk = blockIdx.y * BN;
    const int lm = lane & 15, lq = lane >> 4;
    const int sr = lane >> 2, sc = (lane & 3) << 3;
    const int f = (OUT_MODE == 2) ? flag[0] : 0;

    f32x4 acc[MT][NT];
#pragma unroll
    for (int i = 0; i < MT; ++i)
#pragma unroll
        for (int j = 0; j < NT; ++j) acc[i][j] = (f32x4){0.f, 0.f, 0.f, 0.f};

    auto stage = [&](int buf, int kb) {
#pragma unroll
        for (int cch = 0; cch < 2; ++cch) {
#pragma unroll
            for (int i = 0; i < (BM + 63) / 64; ++i) {
                int row = i * 64 + w * 16;
                if (row < BM)
                    gload16(A + (size_t)(m_blk + row + sr) * K + kb + cch * 32 + sc,
                            &As[buf][cch * BM * 32 + row * 32]);
            }
#pragma unroll
            for (int i = 0; i < (BN + 63) / 64; ++i) {
                int row = i * 64 + w * 16;
                if (row < BN)
                    gload16(Bt + (size_t)(n_blk + row + sr) * K + kb + cch * 32 + sc,
                            &Bs[buf][cch * BN * 32 + row * 32]);
            }
        }
    };
    auto compute = [&](int buf) {
#pragma unroll
        for (int cch = 0; cch < 2; ++cch) {
            bf16x8 af[MT], bf[NT];
#pragma unroll
            for (int tm = 0; tm < MT; ++tm)
                af[tm] = *(const bf16x8*)(&As[buf][cch * BM * 32 +
                                                   (wm * 16 * MT + tm * 16 + lm) * 32 + lq * 8]);
#pragma unroll
            for (int tn = 0; tn < NT; ++tn)
                bf[tn] = *(const bf16x8*)(&Bs[buf][cch * BN * 32 +
                                                   (wn * 16 * NT + tn * 16 + lm) * 32 + lq * 8]);
#pragma unroll
            for (int tm = 0; tm < MT; ++tm)
#pragma unroll
                for (int tn = 0; tn < NT; ++tn)
                    acc[tm][tn] = __builtin_amdgcn_mfma_f32_16x16x32_bf16(af[tm], bf[tn],
                                                                          acc[tm][tn], 0, 0, 0);
        }
    };

    stage(0, 0);
    __syncthreads();
    int cur = 0;
    for (int kb = 64; kb < K; kb += 64) {
        stage(cur ^ 1, kb);
        compute(cur);
        __syncthreads();
        cur ^= 1;
    }
    compute(cur);

#pragma unroll
    for (int tm = 0; tm < MT; ++tm)
#pragma unroll
        for (int tn = 0; tn < NT; ++tn)
#pragma unroll
            for (int r = 0; r < 4; ++r) {
                int row = m_blk + wm * 16 * MT + tm * 16 + lq * 4 + r;
                int col = n_blk + wn * 16 * NT + tn * 16 + lm;
                float v = acc[tm][tn][r];
                if (OUT_MODE == 1) {
                    ((u16*)C)[(size_t)row * N + col] = f2b(v);
                } else {  // 2: dual
                    if (f) ((u16*)C)[(size_t)row * N + col] = f2b(v);
                    else   ((float*)C)[(size_t)row * N + col] = v;
                }
            }
}

// ---------------- gemm2 fused: A = silu(causal_dw_conv(xz[:, :2048])) computed in-staging ----
// BM=32, K split 16 ways (KLEN=128) -> grid (32,1,16) = 512 blocks = 2/CU (was 128 = 0.5/CU).
// A-stage: thread = t-row (tid>>3) x 8-d group (tid&7)*8 spanning a 64-k step.
__global__ __launch_bounds__(256) void gemm2_conv_k(const u16* __restrict__ xz,
                                                    const u16* __restrict__ Bt,   // W_x_t [128,2048]
                                                    float* __restrict__ parts,
                                                    u16* __restrict__ xconv,
                                                    const void* __restrict__ cw,
                                                    const void* __restrict__ cb,
                                                    const int* __restrict__ flag) {
    constexpr int MT = 1, NT = 4;
    constexpr int BM = 32, BN = 128, K = 2048, KLEN = 128;
    __shared__ __align__(16) u16 As[2][2 * BM * 32];
    __shared__ __align__(16) u16 Bs[2][2 * BN * 32];
    __shared__ __align__(16) float cws[KLEN * 4];
    __shared__ float cbs[KLEN];
    const int tid = threadIdx.x;
    const int w = tid >> 6, lane = tid & 63;
    const int wm = w & 1, wn = w >> 1;
    const int m_blk = blockIdx.x * BM;
    const int kb0 = blockIdx.z * KLEN;
    const int lm = lane & 15, lq = lane >> 4;
    const int sr = lane >> 2, sc = (lane & 3) << 3;
    const int f = flag[0];

    if (tid < KLEN) {   // conv weights/bias for this block's d-slice -> LDS
#pragma unroll
        for (int k = 0; k < 4; ++k) cws[tid * 4 + k] = rdf(cw, (size_t)(kb0 + tid) * 4 + k, f);
        cbs[tid] = rdf(cb, kb0 + tid, f);
    }
    __syncthreads();  // cws/cbs visible before any A-stage

    f32x4 acc[MT][NT];
#pragma unroll
    for (int i = 0; i < MT; ++i)
#pragma unroll
        for (int j = 0; j < NT; ++j) acc[i][j] = (f32x4){0.f, 0.f, 0.f, 0.f};

    const int arow = tid >> 3;          // 0..31: output t-row
    const int ag = (tid & 7) << 3;      // 0..56: d-offset within the 64-k step
    const int trow = m_blk + arow;

    auto bstage = [&](int buf, int kb) {
#pragma unroll
        for (int cch = 0; cch < 2; ++cch)
#pragma unroll
            for (int i = 0; i < BN / 64; ++i) {
                int row = i * 64 + w * 16;
                gload16(Bt + (size_t)(row + sr) * K + kb + cch * 32 + sc,
                        &Bs[buf][cch * BN * 32 + row * 32]);
            }
    };
    auto astage = [&](int buf, int kb) {   // covers the full 64-k step
        const int d = kb + ag;
        const int dl = kb - kb0 + ag;
        bf16x8 xv[4];
#pragma unroll
        for (int kk = 0; kk < 4; ++kk) {
            bf16x8 zz = {0, 0, 0, 0, 0, 0, 0, 0};
            int tt = trow + kk - 3;
            xv[kk] = (tt >= 0) ? *(const bf16x8*)(xz + (size_t)tt * 4096 + d) : zz;
        }
        bf16x8 rv;
#pragma unroll
        for (int j = 0; j < 8; ++j) {
            f32x4 wv = *(const f32x4*)(cws + (dl + j) * 4);
            float a = cbs[dl + j];
#pragma unroll
            for (int kk = 0; kk < 4; ++kk) a += b2f((u16)xv[kk][j]) * wv[kk];
            rv[j] = (short)f2b(a * fsig(a));
        }
        *(bf16x8*)(&As[buf][(ag >> 5) * BM * 32 + arow * 32 + (ag & 31)]) = rv;
        *(bf16x8*)(xconv + (size_t)trow * 2048 + d) = rv;
    };
    auto compute = [&](int buf) {
#pragma unroll
        for (int cch = 0; cch < 2; ++cch) {
            bf16x8 af[MT], bf[NT];
#pragma unroll
            for (int tm = 0; tm < MT; ++tm)
                af[tm] = *(const bf16x8*)(&As[buf][cch * BM * 32 +
                                                   (wm * 16 * MT + tm * 16 + lm) * 32 + lq * 8]);
#pragma unroll
            for (int tn = 0; tn < NT; ++tn)
                bf[tn] = *(const bf16x8*)(&Bs[buf][cch * BN * 32 +
                                                   (wn * 16 * NT + tn * 16 + lm) * 32 + lq * 8]);
#pragma unroll
            for (int tm = 0; tm < MT; ++tm)
#pragma unroll
                for (int tn = 0; tn < NT; ++tn)
                    acc[tm][tn] = __builtin_amdgcn_mfma_f32_16x16x32_bf16(af[tm], bf[tn],
                                                                          acc[tm][tn], 0, 0, 0);
        }
    };

    bstage(0, kb0);
    astage(0, kb0);
    __syncthreads();
    int cur = 0;
    for (int kb = kb0 + 64; kb < kb0 + KLEN; kb += 64) {
        bstage(cur ^ 1, kb);       // async loads first (in flight during A VALU + MFMA)
        astage(cur ^ 1, kb);
        compute(cur);
        __syncthreads();
        cur ^= 1;
    }
    compute(cur);

#pragma unroll
    for (int tm = 0; tm < MT; ++tm)
#pragma unroll
        for (int tn = 0; tn < NT; ++tn)
#pragma unroll
            for (int r = 0; r < 4; ++r) {
                int row = m_blk + wm * 16 * MT + tm * 16 + lq * 4 + r;
                int col = wn * 64 + tn * 16 + lm;
                parts[(size_t)blockIdx.z * 131072 + (size_t)row * 128 + col] = acc[tm][tn][r];
            }
}

// ---- in-block delta tile: dlt[32 t][128 d] = softplus(bf16(sum parts dt-cols) @ W_dt_t + b) ----
__device__ __forceinline__ void delta_tile(const float* __restrict__ parts,
                                           const u16* __restrict__ Wdt,  // W_dt_t [2048,64]
                                           const void* __restrict__ bias,
                                           int f, int t0, int d0,
                                           u16* As2, u16* Bs2, float (*dlt)[128],
                                           int tid, int w, int lm, int lq, int sr, int sc) {
#pragma unroll
    for (int cch = 0; cch < 2; ++cch)
#pragma unroll
        for (int i = 0; i < 2; ++i) {
            int row = i * 64 + w * 16;
            gload16(Wdt + (size_t)(d0 + row + sr) * 64 + cch * 32 + sc,
                    Bs2 + cch * 4096 + row * 32);
        }
    {
        int arow = tid >> 3, acg = (tid & 7) << 3;
        f32x4 s0 = {0.f, 0.f, 0.f, 0.f}, s1 = {0.f, 0.f, 0.f, 0.f};
#pragma unroll
        for (int sl = 0; sl < NSL; ++sl) {
            const float* p = parts + (size_t)sl * 131072 + (size_t)(t0 + arow) * 128 + acg;
            s0 += *(const f32x4*)p;
            s1 += *(const f32x4*)(p + 4);
        }
        bf16x8 rv;
#pragma unroll
        for (int j = 0; j < 4; ++j) {
            rv[j] = (short)f2b(s0[j]);
            rv[4 + j] = (short)f2b(s1[j]);
        }
        *(bf16x8*)(As2 + (acg >> 5) * 1024 + arow * 32 + (acg & 31)) = rv;
    }
    __syncthreads();  // As2/Bs2 (and caller's BCs) ready

    f32x4 dacc[2][2];
#pragma unroll
    for (int i = 0; i < 2; ++i)
#pragma unroll
        for (int j = 0; j < 2; ++j) dacc[i][j] = (f32x4){0.f, 0.f, 0.f, 0.f};
#pragma unroll
    for (int cch = 0; cch < 2; ++cch) {
        bf16x8 af[2], bf[2];
#pragma unroll
        for (int tm = 0; tm < 2; ++tm)
            af[tm] = *(const bf16x8*)(As2 + cch * 1024 + (tm * 16 + lm) * 32 + lq * 8);
#pragma unroll
        for (int tn = 0; tn < 2; ++tn)
            bf[tn] = *(const bf16x8*)(Bs2 + cch * 4096 + (w * 32 + tn * 16 + lm) * 32 + lq * 8);
#pragma unroll
        for (int tm = 0; tm < 2; ++tm)
#pragma unroll
            for (int tn = 0; tn < 2; ++tn)
                dacc[tm][tn] = __builtin_amdgcn_mfma_f32_16x16x32_bf16(af[tm], bf[tn],
                                                                       dacc[tm][tn], 0, 0, 0);
    }
#pragma unroll
    for (int tm = 0; tm < 2; ++tm)
#pragma unroll
        for (int tn = 0; tn < 2; ++tn)
#pragma unroll
            for (int r = 0; r < 4; ++r) {
                int row = tm * 16 + lq * 4 + r;
                int col = w * 32 + tn * 16 + lm;
                float b = rdf(bias, d0 + col, f);
                float t2 = dacc[tm][tn][r] + b;
                dlt[row][col] = fmaxf(t2, 0.f) + __logf(1.f + __expf(-fabsf(t2)));
            }
    __syncthreads();  // dlt ready
}

// ---------------- scan1: delta in-block; local scan; PERSIST dlt(fp32)+BC sums for scan3 ------
__global__ __launch_bounds__(256) void scan1_k(const u16* __restrict__ xc,
                                               const float* __restrict__ parts,
                                               const u16* __restrict__ Wdt,
                                               const void* __restrict__ bias,
                                               const void* __restrict__ A_log,
                                               float* __restrict__ Acar,
                                               float* __restrict__ Bcar,
                                               float* __restrict__ deltag,
                                               float* __restrict__ bcg,
                                               const int* __restrict__ flag) {
    __shared__ __align__(16) u16 As2[2 * 32 * 32];    // 4 KB
    __shared__ __align__(16) u16 Bs2[2 * 128 * 32];   // 16 KB
    __shared__ __align__(16) float dlt[32][128];      // 16 KB
    __shared__ __align__(16) float BCs[32][32];       // 4 KB
    const int f = *flag;
    const int tid = threadIdx.x, b = blockIdx.x;
    const int w = tid >> 6, lane = tid & 63;
    const int lm = lane & 15, lq = lane >> 4;
    const int sr = lane >> 2, sc = (lane & 3) << 3;
    const int c = b >> 4, dblk = b & 15;
    const int d0 = dblk * 128;
    const int t0 = c * 32;
    {
        int idx = tid * 4;
        int tl = idx >> 5, col = idx & 31;
        f32x4 s = {0.f, 0.f, 0.f, 0.f};
#pragma unroll
        for (int sl = 0; sl < NSL; ++sl)
            s += *(const f32x4*)(parts + (size_t)sl * 131072 + (size_t)(t0 + tl) * 128 + 64 + col);
        *(f32x4*)&BCs[tl][col] = s;
    }
    delta_tile(parts, Wdt, bias, f, t0, d0, As2, Bs2, dlt, tid, w, lm, lq, sr, sc);

    // persist dlt fp32 (scan3 re-reads instead of re-staging parts + MFMAs)
#pragma unroll
    for (int k = 0; k < 4; ++k) {
        int kk = tid + k * 256;                  // 0..1023 over 32x(128/4)
        int row = kk >> 5, col4 = (kk & 31) << 2;
        *(f32x4*)(deltag + (size_t)(t0 + row) * 2048 + d0 + col4) = *(const f32x4*)&dlt[row][col4];
    }
    // persist BC sums once per chunk (identical across the 16 dblk blocks)
    if (dblk == 0) {
        int idx = tid * 4;
        int tl = idx >> 5, col = idx & 31;
        *(f32x4*)(bcg + c * 1024 + tl * 32 + col) = *(const f32x4*)&BCs[tl][col];
    }

    const int dl = tid >> 1, nh = tid & 1;
    const int d = d0 + dl, n0 = nh << 3;
    float A[8], P[8], h[8];
#pragma unroll
    for (int j = 0; j < 8; ++j) {
        A[j] = -__expf(rdf(A_log, d * 16 + n0 + j, f));
        P[j] = 1.f;
        h[j] = 0.f;
    }
#pragma unroll 4
    for (int i = 0; i < 32; ++i) {
        int t = t0 + i;
        float de = dlt[i][dl];
        float dBu = de * b2f(xc[t * 2048 + d]);
        f32x4 Bv0 = *(const f32x4*)&BCs[i][n0];
        f32x4 Bv1 = *(const f32x4*)&BCs[i][n0 + 4];
#pragma unroll
        for (int j = 0; j < 8; ++j) {
            float Bv = (j < 4) ? Bv0[j & 3] : Bv1[j & 3];
            float a = __expf(de * A[j]);
            h[j] = a * h[j] + Bv * dBu;
            P[j] *= a;
        }
    }
    f32x4 pa0 = {P[0], P[1], P[2], P[3]}, pa1 = {P[4], P[5], P[6], P[7]};
    f32x4 hb0 = {h[0], h[1], h[2], h[3]}, hb1 = {h[4], h[5], h[6], h[7]};
    size_t base = (size_t)c * 32768 + d * 16 + n0;
    *(f32x4*)(Acar + base) = pa0;
    *(f32x4*)(Acar + base + 4) = pa1;
    *(f32x4*)(Bcar + base) = hb0;
    *(f32x4*)(Bcar + base + 4) = hb1;
}

// ---------------- scan3: load persisted dlt/BCs; inline lookback over raw carries -------------
__global__ __launch_bounds__(256) void scan3_k(const u16* __restrict__ xc,
                                               const float* __restrict__ deltag,
                                               const float* __restrict__ bcg,
                                               const u16* __restrict__ xz,
                                               const void* __restrict__ A_log,
                                               const void* __restrict__ Dvp,
                                               const float* __restrict__ Acar,
                                               const float* __restrict__ Bcar,
                                               u16* __restrict__ yg,
                                               const int* __restrict__ flag) {
    __shared__ __align__(16) float dlt[32][128];      // 16 KB
    __shared__ __align__(16) float BCs[32][32];       // 4 KB
    const int f = *flag;
    const int tid = threadIdx.x, b = blockIdx.x;
    const int c = b >> 4;
    const int d0 = (b & 15) * 128;
    const int t0 = c * 32;
    {
        int idx = tid * 4;
        int tl = idx >> 5, col = idx & 31;
        *(f32x4*)&BCs[tl][col] = *(const f32x4*)(bcg + c * 1024 + tl * 32 + col);
    }
#pragma unroll
    for (int k = 0; k < 4; ++k) {
        int kk = tid + k * 256;
        int row = kk >> 5, col4 = (kk & 31) << 2;
        *(f32x4*)&dlt[row][col4] = *(const f32x4*)(deltag + (size_t)(t0 + row) * 2048 + d0 + col4);
    }
    __syncthreads();

    const int dl = tid >> 1, nh = tid & 1;
    const int d = d0 + dl, n0 = nh << 3;
    float A[8], h[8];
#pragma unroll
    for (int j = 0; j < 8; ++j) {
        A[j] = -__expf(rdf(A_log, d * 16 + n0 + j, f));
        h[j] = 0.f;
    }
    // inline lookback (replaces scan2): compose raw carries ascending
    for (int cc = 0; cc < c; ++cc) {
        size_t cb = (size_t)cc * 32768 + d * 16 + n0;
        f32x4 a0 = *(const f32x4*)(Acar + cb);
        f32x4 a1 = *(const f32x4*)(Acar + cb + 4);
        f32x4 b0 = *(const f32x4*)(Bcar + cb);
        f32x4 b1 = *(const f32x4*)(Bcar + cb + 4);
#pragma unroll
        for (int j = 0; j < 4; ++j) {
            h[j] = a0[j] * h[j] + b0[j];
            h[4 + j] = a1[j] * h[4 + j] + b1[j];
        }
    }

    float Dd = rdf(Dvp, d, f);
#pragma unroll 4
    for (int i = 0; i < 32; ++i) {
        int t = t0 + i;
        float de = dlt[i][dl];
        float u = b2f(xc[t * 2048 + d]);
        float dBu = de * u;
        f32x4 Bv0 = *(const f32x4*)&BCs[i][n0];
        f32x4 Bv1 = *(const f32x4*)&BCs[i][n0 + 4];
        f32x4 Cv0 = *(const f32x4*)&BCs[i][16 + n0];
        f32x4 Cv1 = *(const f32x4*)&BCs[i][20 + n0];
        float p = 0.f;
#pragma unroll
        for (int j = 0; j < 8; ++j) {
            float Bv = (j < 4) ? Bv0[j & 3] : Bv1[j & 3];
            float Cv = (j < 4) ? Cv0[j & 3] : Cv1[j & 3];
            float a = __expf(de * A[j]);
            h[j] = a * h[j] + Bv * dBu;
            p += h[j] * Cv;
        }
        p += __shfl_xor(p, 1);  // combine the two n-halves (lanes 2k,2k+1 share d)
        if (nh == 0) {
            float r = b2f(xz[(size_t)t * 4096 + 2048 + d]);
            float yt = p + u * Dd;
            yg[t * 2048 + d] = f2b(yt * r * fsig(r));
        }
    }
}

// ---------------- fallback path (small ws): gemm3 -> delta, then monolithic scan --------------
__global__ __launch_bounds__(256) void gemm3_red_k(const float* __restrict__ parts,
                                                   const u16* __restrict__ Bt,   // W_dt_t [2048,64]
                                                   float* __restrict__ delta,
                                                   const void* __restrict__ bias,
                                                   const int* __restrict__ flag) {
    constexpr int MT = 2, NT = 2, BM = 64, BN = 64, K = 64;
    __shared__ __align__(16) u16 As[2 * BM * 32];
    __shared__ __align__(16) u16 Bs[2 * BN * 32];
    const int tid = threadIdx.x;
    const int w = tid >> 6, lane = tid & 63;
    const int wm = w & 1, wn = w >> 1;
    const int m_blk = blockIdx.x * BM, n_blk = blockIdx.y * BN;
    const int lm = lane & 15, lq = lane >> 4;
    const int sr = lane >> 2, sc = (lane & 3) << 3;
    const int f = flag[0];

    f32x4 acc[MT][NT];
#pragma unroll
    for (int i = 0; i < MT; ++i)
#pragma unroll
        for (int j = 0; j < NT; ++j) acc[i][j] = (f32x4){0.f, 0.f, 0.f, 0.f};

    const int arow = tid >> 2;
    const int acg = (tid & 3) << 3;

#pragma unroll
    for (int cch = 0; cch < 2; ++cch) {
        int row = w * 16;
        gload16(Bt + (size_t)(n_blk + row + sr) * K + cch * 32 + sc, &Bs[cch * BN * 32 + row * 32]);
    }
#pragma unroll
    for (int cch = 0; cch < 2; ++cch) {
        f32x4 s0 = {0.f, 0.f, 0.f, 0.f}, s1 = {0.f, 0.f, 0.f, 0.f};
#pragma unroll
        for (int sl = 0; sl < NSL; ++sl) {
            const float* p = parts + (size_t)sl * 131072 + (size_t)(m_blk + arow) * 128 + cch * 32 + acg;
            s0 += *(const f32x4*)p;
            s1 += *(const f32x4*)(p + 4);
        }
        bf16x8 rv;
#pragma unroll
        for (int j = 0; j < 4; ++j) {
            rv[j] = (short)f2b(s0[j]);
            rv[4 + j] = (short)f2b(s1[j]);
        }
        *(bf16x8*)(&As[cch * BM * 32 + arow * 32 + acg]) = rv;
    }
    __syncthreads();

#pragma unroll
    for (int cch = 0; cch < 2; ++cch) {
        bf16x8 af[MT], bf[NT];
#pragma unroll
        for (int tm = 0; tm < MT; ++tm)
            af[tm] = *(const bf16x8*)(&As[cch * BM * 32 + (wm * 32 + tm * 16 + lm) * 32 + lq * 8]);
#pragma unroll
        for (int tn = 0; tn < NT; ++tn)
            bf[tn] = *(const bf16x8*)(&Bs[cch * BN * 32 + (wn * 32 + tn * 16 + lm) * 32 + lq * 8]);
#pragma unroll
        for (int tm = 0; tm < MT; ++tm)
#pragma unroll
            for (int tn = 0; tn < NT; ++tn)
                acc[tm][tn] = __builtin_amdgcn_mfma_f32_16x16x32_bf16(af[tm], bf[tn],
                                                                      acc[tm][tn], 0, 0, 0);
    }

#pragma unroll
    for (int tm = 0; tm < MT; ++tm)
#pragma unroll
        for (int tn = 0; tn < NT; ++tn)
#pragma unroll
            for (int r = 0; r < 4; ++r) {
                int row = m_blk + wm * 32 + tm * 16 + lq * 4 + r;
                int col = n_blk + wn * 32 + tn * 16 + lm;
                float b = rdf(bias, col, f);
                float t2 = acc[tm][tn][r] + b;
                float sp = fmaxf(t2, 0.f) + __logf(1.f + __expf(-fabsf(t2)));
                delta[(size_t)row * 2048 + col] = sp;
            }
}

__global__ __launch_bounds__(256) void scan_k(const float* __restrict__ delta,
                                              const u16* __restrict__ xc,
                                              const float* __restrict__ parts,
                                              const u16* __restrict__ xz,
                                              const void* __restrict__ A_log,
                                              const void* __restrict__ Dvp,
                                              u16* __restrict__ yg,
                                              const int* __restrict__ flag) {
    int f = *flag;
    int g = blockIdx.x * 256 + threadIdx.x;
    int d = g >> 4, n = g & 15;
    float A = -__expf(rdf(A_log, d * 16 + n, f));
    float Dd = rdf(Dvp, d, f);
    float h = 0.f;
    for (int t = 0; t < LSEQ; ++t) {
        float de = delta[t * 2048 + d];
        float u = b2f(xc[t * 2048 + d]);
        float Bv = 0.f, Cv = 0.f;
#pragma unroll
        for (int sl = 0; sl < NSL; ++sl) {
            Bv += parts[(size_t)sl * 131072 + (size_t)t * 128 + 64 + n];
            Cv += parts[(size_t)sl * 131072 + (size_t)t * 128 + 80 + n];
        }
        h = __expf(de * A) * h + (de * Bv) * u;
        float p = h * Cv;
        p += __shfl_xor(p, 1);
        p += __shfl_xor(p, 2);
        p += __shfl_xor(p, 4);
        p += __shfl_xor(p, 8);
        if (n == 0) {
            float r = b2f(xz[(size_t)t * 4096 + 2048 + d]);
            float yt = p + u * Dd;
            yg[t * 2048 + d] = f2b(yt * r * fsig(r));
        }
    }
}

extern "C" void kernel_launch(void* const* d_in, const int* in_sizes, int n_in,
                              void* d_out, int out_size, void* d_ws, size_t ws_size,
                              hipStream_t stream) {
    const void* x      = d_in[0];
    const void* W_in   = d_in[1];
    const void* conv_w = d_in[2];
    const void* conv_b = d_in[3];
    const void* W_x    = d_in[4];
    const void* W_dt   = d_in[5];
    const void* b_dt   = d_in[6];
    const void* A_log  = d_in[7];
    const void* Dv     = d_in[8];
    const void* W_out  = d_in[9];

    char* ws = (char*)d_ws;
    u16*   xz     = (u16*)(ws);               // [1024,4096] bf16 = 8388608       -> 8388608
    u16*   xconv  = (u16*)(ws + 8388608);     // [1024,2048] bf16 = 4194304       -> 12582912
    float* parts  = (float*)(ws + 12582912);  // [16,1024,128] fp32 = 8388608     -> 20971520
    u16*   W_in_t = (u16*)(ws + 20971520);    // W_in^T [4096,1024] = 8388608     -> 29360128
    u16*   yg     = (u16*)(ws + 29360128);    // [1024,2048] bf16 = 4194304       -> 33554432
    u16*   xb     = (u16*)(ws + 29360128);    // alias yg: x bf16, gemm1 only
    u16*   W_x_t  = (u16*)(ws + 33554432);    // W_x^T padded [128,2048] = 524288 -> 34078720
    u16*   W_dt_t = (u16*)(ws + 34078720);    // W_dt^T [2048,64] = 262144        -> 34340864
    u16*   W_out_t= (u16*)(ws + 34340864);    // W_out^T [1024,2048] = 4194304    -> 38535168
    int*   flag   = (int*)(ws + 38535168);    // 4 B (pad to 38535296)
    float* Acar   = (float*)(ws + 38535296);  // 4194304 -> 42729600
    float* Bcar   = (float*)(ws + 42729600);  // 4194304 -> 46923904
    float* deltag = (float*)(ws + 46923904);  // [1024,2048] fp32 = 8388608 -> 55312512
    float* bcg    = (float*)(ws + 55312512);  // [32,1024] fp32 = 131072 -> 55443584
    float* dfb    = (float*)(ws + 38535296);  // fallback delta alias (Acar+Bcar region)
    const bool chunked_ok = (ws_size >= 55443584);

    // 0) prep: detect + x->bf16 + W_in^T only (other transposes ride gemm1)
    prep_k<<<5120, 256, 0, stream>>>(x, W_in, xb, W_in_t, flag);
    // 1) gemm1 FAT: xz = xb @ W_in^T (512 gemm blocks = 2/CU) + 2432 transpose riders
    gemm1_fat_k<<<dim3(16, 184), 256, 0, stream>>>(xb, W_in_t, xz,
                                                   W_out, W_x, W_dt,
                                                   W_out_t, W_x_t, W_dt_t, flag);
    // 2+3) x_dbl partials = silu(conv(x_in)) @ W_x^T; BM=32, K split 16 ways ->
    //      512 blocks = 2/CU (was 128 = 0.5/CU; only scan1 pays the extra slice reads now)
    gemm2_conv_k<<<dim3(32, 1, 16), 256, 0, stream>>>(xz, W_x_t, parts, xconv,
                                                      conv_w, conv_b, flag);

    // 4+5) scan: 2 dispatches. scan1 computes delta in-block + persists dlt/BC sums;
    //      scan3 reloads them and inlines the lookback (dispatch boundary = the sync).
    if (chunked_ok) {
        scan1_k<<<512, 256, 0, stream>>>(xconv, parts, W_dt_t, b_dt, A_log, Acar, Bcar,
                                         deltag, bcg, flag);
        scan3_k<<<512, 256, 0, stream>>>(xconv, deltag, bcg, xz, A_log, Dv,
                                         Acar, Bcar, yg, flag);
    } else {
        gemm3_red_k<<<dim3(16, 32), 256, 0, stream>>>(parts, W_dt_t, dfb, b_dt, flag);
        scan_k<<<128, 256, 0, stream>>>(dfb, xconv, parts, xz, A_log, Dv, yg, flag);
    }

    // 6) out = yg @ W_out  [1024,1024]  (32x64 tiles, 512 blocks = 2/CU per R8 lesson)
    gemm_bt<1, 2, 2><<<dim3(32, 16), 256, 0, stream>>>(yg, W_out_t, d_out,
                                                       1024, 1024, 2048, flag);
}

// Round 15
// 198.186 us; speedup vs baseline: 1.0244x; 1.0244x over previous
//
#include <hip/hip_runtime.h>

typedef unsigned short u16;
typedef unsigned int u32;
typedef __attribute__((ext_vector_type(8))) short bf16x8;
typedef __attribute__((ext_vector_type(4))) float f32x4;

#define LSEQ 1024
#define NSL 8  // k-slices for gemm2 / parts

__device__ __forceinline__ float b2f(u16 v) { return __uint_as_float(((u32)v) << 16); }
__device__ __forceinline__ u16 f2b(float f) {
    u32 x = __float_as_uint(f);
    return (u16)((x + 0x7fffu + ((x >> 16) & 1u)) >> 16);
}
__device__ __forceinline__ float rdf(const void* p, size_t i, int f) {
    return f ? b2f(((const u16*)p)[i]) : ((const float*)p)[i];
}
__device__ __forceinline__ float fsig(float x) {
    return __builtin_amdgcn_rcpf(1.f + __expf(-x));
}

typedef const __attribute__((address_space(1))) u32* gp_t;
typedef __attribute__((address_space(3))) u32* lp_t;
__device__ __forceinline__ void gload16(const u16* g, u16* lds_wave_base) {
    __builtin_amdgcn_global_load_lds((gp_t)g, (lp_t)lds_wave_base, 16, 0, 0);
}

// shared transpose-tile body: dst[Cp,R] = src[R,Cn]^T (zero-padded cols >= Cn)
__device__ __forceinline__ void transpose_tile(const void* src, u16* dst, int R, int Cn,
                                               int br, int bc, int f, u16 (*tile)[36]) {
    int r0 = br * 32, c0 = bc * 32;
    {
        int ty = threadIdx.x >> 3, tx4 = (threadIdx.x & 7) << 2;
        u16 o0 = 0, o1 = 0, o2 = 0, o3 = 0;
        if (c0 + tx4 < Cn) {
            size_t off = (size_t)(r0 + ty) * Cn + c0 + tx4;
            if (f) {
                ushort4 u = *(const ushort4*)((const u16*)src + off);
                o0 = u.x; o1 = u.y; o2 = u.z; o3 = u.w;
            } else {
                float4 v = *(const float4*)((const float*)src + off);
                o0 = f2b(v.x); o1 = f2b(v.y); o2 = f2b(v.z); o3 = f2b(v.w);
            }
        }
        *(ushort4*)(&tile[ty][tx4]) = make_ushort4(o0, o1, o2, o3);
    }
    __syncthreads();
    {
        int cc = threadIdx.x >> 3, r4 = (threadIdx.x & 7) << 2;
        ushort4 o = make_ushort4(tile[r4][cc], tile[r4 + 1][cc], tile[r4 + 2][cc], tile[r4 + 3][cc]);
        *(ushort4*)(dst + (size_t)(c0 + cc) * R + r0 + r4) = o;
    }
}

// ---------------- prep: dtype detect + x->bf16 + W_in^T ONLY (other transposes ride gemm1) ----
__global__ __launch_bounds__(256) void prep_k(const void* __restrict__ x,
                                              const void* __restrict__ W_in,
                                              u16* __restrict__ xb,
                                              u16* __restrict__ W_in_t,
                                              int* __restrict__ flag) {
    __shared__ int cnt;
    __shared__ __align__(8) u16 tile[32][36];
    if (threadIdx.x == 0) cnt = 0;
    __syncthreads();
    const u16* xu = (const u16*)x;
    int c = 0;
#pragma unroll
    for (int j = 0; j < 8; ++j) {
        u16 u = xu[threadIdx.x * 8 + j];
        int e = (u >> 7) & 0xFF;
        c += (e == 0 || (e >= 100 && e <= 140)) ? 1 : 0;
    }
    atomicAdd(&cnt, c);
    __syncthreads();
    const int f = (cnt >= 1638) ? 1 : 0;
    if (blockIdx.x == 0 && threadIdx.x == 0) *flag = f;

    int blk = blockIdx.x;
    if (blk < 1024) {  // x -> bf16, 4 elems/thread
        int i = (blk * 256 + threadIdx.x) * 4;
        ushort4 o;
        if (f) {
            o = *(const ushort4*)(xu + i);
        } else {
            float4 v = *(const float4*)((const float*)x + i);
            o = make_ushort4(f2b(v.x), f2b(v.y), f2b(v.z), f2b(v.w));
        }
        *(ushort4*)(xb + i) = o;
        return;
    }
    blk -= 1024;   // 0..4095: W_in [1024,4096] -> W_in_t, nbc=128
    transpose_tile(W_in, W_in_t, 1024, 4096, blk / 128, blk % 128, f, tile);
}

// ---------------- gemm1 FAT: xz = xb @ W_in_t^T  +  rider blocks do W_out/W_x/W_dt transposes --
// grid (16, 32+152): blockIdx.y < 32 -> 64x128 gemm tile; else rider id in [0,2432).
__global__ __launch_bounds__(256) void gemm1_fat_k(const u16* __restrict__ A,
                                                   const u16* __restrict__ Bt,
                                                   u16* __restrict__ C,
                                                   const void* __restrict__ W_out,
                                                   const void* __restrict__ W_x,
                                                   const void* __restrict__ W_dt,
                                                   u16* __restrict__ W_out_t,
                                                   u16* __restrict__ W_x_t,
                                                   u16* __restrict__ W_dt_t,
                                                   const int* __restrict__ flag) {
    constexpr int MT = 2, NT = 4, BM = 64, BN = 128, N = 4096, K = 1024;
    __shared__ __align__(16) u16 As[2][2 * BM * 32];
    __shared__ __align__(16) u16 Bs[2][2 * BN * 32];
    __shared__ __align__(8) u16 tile[32][36];
    if (blockIdx.y >= 32) {  // ---- transpose rider ----
        int id = (blockIdx.y - 32) * 16 + blockIdx.x;  // 0..2431
        const int f = flag[0];
        const void* src; u16* dst; int R, Cn, nbc, t;
        if (id < 2048)      { src = W_out; dst = W_out_t; R = 2048; Cn = 1024; nbc = 32; t = id; }
        else if (id < 2304) { src = W_x;   dst = W_x_t;   R = 2048; Cn = 96;   nbc = 4;  t = id - 2048; }
        else                { src = W_dt;  dst = W_dt_t;  R = 64;   Cn = 2048; nbc = 64; t = id - 2304; }
        transpose_tile(src, dst, R, Cn, t / nbc, t % nbc, f, tile);
        return;
    }
    const int tid = threadIdx.x;
    const int w = tid >> 6, lane = tid & 63;
    const int wm = w & 1, wn = w >> 1;
    const int m_blk = blockIdx.x * BM, n_blk = blockIdx.y * BN;
    const int lm = lane & 15, lq = lane >> 4;
    const int sr = lane >> 2, sc = (lane & 3) << 3;

    f32x4 acc[MT][NT];
#pragma unroll
    for (int i = 0; i < MT; ++i)
#pragma unroll
        for (int j = 0; j < NT; ++j) acc[i][j] = (f32x4){0.f, 0.f, 0.f, 0.f};

    auto stage = [&](int buf, int kb) {
#pragma unroll
        for (int cch = 0; cch < 2; ++cch) {
#pragma unroll
            for (int i = 0; i < BM / 64; ++i) {
                int row = i * 64 + w * 16;
                gload16(A + (size_t)(m_blk + row + sr) * K + kb + cch * 32 + sc,
                        &As[buf][cch * BM * 32 + row * 32]);
            }
#pragma unroll
            for (int i = 0; i < BN / 64; ++i) {
                int row = i * 64 + w * 16;
                gload16(Bt + (size_t)(n_blk + row + sr) * K + kb + cch * 32 + sc,
                        &Bs[buf][cch * BN * 32 + row * 32]);
            }
        }
    };
    auto compute = [&](int buf) {
#pragma unroll
        for (int cch = 0; cch < 2; ++cch) {
            bf16x8 af[MT], bf[NT];
#pragma unroll
            for (int tm = 0; tm < MT; ++tm)
                af[tm] = *(const bf16x8*)(&As[buf][cch * BM * 32 +
                                                   (wm * 16 * MT + tm * 16 + lm) * 32 + lq * 8]);
#pragma unroll
            for (int tn = 0; tn < NT; ++tn)
                bf[tn] = *(const bf16x8*)(&Bs[buf][cch * BN * 32 +
                                                   (wn * 16 * NT + tn * 16 + lm) * 32 + lq * 8]);
#pragma unroll
            for (int tm = 0; tm < MT; ++tm)
#pragma unroll
                for (int tn = 0; tn < NT; ++tn)
                    acc[tm][tn] = __builtin_amdgcn_mfma_f32_16x16x32_bf16(af[tm], bf[tn],
                                                                          acc[tm][tn], 0, 0, 0);
        }
    };

    stage(0, 0);
    __syncthreads();
    int cur = 0;
    for (int kb = 64; kb < K; kb += 64) {
        stage(cur ^ 1, kb);
        compute(cur);
        __syncthreads();
        cur ^= 1;
    }
    compute(cur);

#pragma unroll
    for (int tm = 0; tm < MT; ++tm)
#pragma unroll
        for (int tn = 0; tn < NT; ++tn)
#pragma unroll
            for (int r = 0; r < 4; ++r) {
                int row = m_blk + wm * 16 * MT + tm * 16 + lq * 4 + r;
                int col = n_blk + wn * 16 * NT + tn * 16 + lm;
                C[(size_t)row * N + col] = f2b(acc[tm][tn][r]);
            }
}

// ---------------- GEMM, B transposed (gemm4): C[M,N] = A[M,K] * Bt[N,K]^T ----------------
// BK=64 dbuf, guarded staging (supports BM<64).
template <int MT, int NT, int OUT_MODE>
__global__ __launch_bounds__(256) void gemm_bt(const u16* __restrict__ A,
                                               const u16* __restrict__ Bt,
                                               void* __restrict__ C,
                                               int M, int N, int K,
                                               const int* __restrict__ flag) {
    constexpr int BM = 32 * MT, BN = 32 * NT;
    __shared__ __align__(16) u16 As[2][2 * BM * 32];
    __shared__ __align__(16) u16 Bs[2][2 * BN * 32];
    const int tid = threadIdx.x;
    const int w = tid >> 6, lane = tid & 63;
    const int wm = w & 1, wn = w >> 1;
    const int m_blk = blockIdx.x * BM, n_blk = blockIdx.y * BN;
    const int lm = lane & 15, lq = lane >> 4;
    const int sr = lane >> 2, sc = (lane & 3) << 3;
    const int f = (OUT_MODE == 2) ? flag[0] : 0;

    f32x4 acc[MT][NT];
#pragma unroll
    for (int i = 0; i < MT; ++i)
#pragma unroll
        for (int j = 0; j < NT; ++j) acc[i][j] = (f32x4){0.f, 0.f, 0.f, 0.f};

    auto stage = [&](int buf, int kb) {
#pragma unroll
        for (int cch = 0; cch < 2; ++cch) {
#pragma unroll
            for (int i = 0; i < (BM + 63) / 64; ++i) {
                int row = i * 64 + w * 16;
                if (row < BM)
                    gload16(A + (size_t)(m_blk + row + sr) * K + kb + cch * 32 + sc,
                            &As[buf][cch * BM * 32 + row * 32]);
            }
#pragma unroll
            for (int i = 0; i < (BN + 63) / 64; ++i) {
                int row = i * 64 + w * 16;
                if (row < BN)
                    gload16(Bt + (size_t)(n_blk + row + sr) * K + kb + cch * 32 + sc,
                            &Bs[buf][cch * BN * 32 + row * 32]);
            }
        }
    };
    auto compute = [&](int buf) {
#pragma unroll
        for (int cch = 0; cch < 2; ++cch) {
            bf16x8 af[MT], bf[NT];
#pragma unroll
            for (int tm = 0; tm < MT; ++tm)
                af[tm] = *(const bf16x8*)(&As[buf][cch * BM * 32 +
                                                   (wm * 16 * MT + tm * 16 + lm) * 32 + lq * 8]);
#pragma unroll
            for (int tn = 0; tn < NT; ++tn)
                bf[tn] = *(const bf16x8*)(&Bs[buf][cch * BN * 32 +
                                                   (wn * 16 * NT + tn * 16 + lm) * 32 + lq * 8]);
#pragma unroll
            for (int tm = 0; tm < MT; ++tm)
#pragma unroll
                for (int tn = 0; tn < NT; ++tn)
                    acc[tm][tn] = __builtin_amdgcn_mfma_f32_16x16x32_bf16(af[tm], bf[tn],
                                                                          acc[tm][tn], 0, 0, 0);
        }
    };

    stage(0, 0);
    __syncthreads();
    int cur = 0;
    for (int kb = 64; kb < K; kb += 64) {
        stage(cur ^ 1, kb);
        compute(cur);
        __syncthreads();
        cur ^= 1;
    }
    compute(cur);

#pragma unroll
    for (int tm = 0; tm < MT; ++tm)
#pragma unroll
        for (int tn = 0; tn < NT; ++tn)
#pragma unroll
            for (int r = 0; r < 4; ++r) {
                int row = m_blk + wm * 16 * MT + tm * 16 + lq * 4 + r;
                int col = n_blk + wn * 16 * NT + tn * 16 + lm;
                float v = acc[tm][tn][r];
                if (OUT_MODE == 1) {
                    ((u16*)C)[(size_t)row * N + col] = f2b(v);
                } else {  // 2: dual
                    if (f) ((u16*)C)[(size_t)row * N + col] = f2b(v);
                    else   ((float*)C)[(size_t)row * N + col] = v;
                }
            }
}

// ---------------- gemm2 fused: A = silu(causal_dw_conv(xz[:, :2048])) computed in-staging ----
// BM=32, K split 8 ways (KLEN=256) -> grid (32,1,8) = 256 blocks = 1/CU (R13 was 0.5/CU;
// NSL stays 8 so scan1's parts traffic is unchanged — the clean component of R14's bundle).
__global__ __launch_bounds__(256) void gemm2_conv_k(const u16* __restrict__ xz,
                                                    const u16* __restrict__ Bt,   // W_x_t [128,2048]
                                                    float* __restrict__ parts,
                                                    u16* __restrict__ xconv,
                                                    const void* __restrict__ cw,
                                                    const void* __restrict__ cb,
                                                    const int* __restrict__ flag) {
    constexpr int MT = 1, NT = 4;
    constexpr int BM = 32, BN = 128, K = 2048, KLEN = 256;
    __shared__ __align__(16) u16 As[2][2 * BM * 32];
    __shared__ __align__(16) u16 Bs[2][2 * BN * 32];
    __shared__ __align__(16) float cws[KLEN * 4];
    __shared__ float cbs[KLEN];
    const int tid = threadIdx.x;
    const int w = tid >> 6, lane = tid & 63;
    const int wm = w & 1, wn = w >> 1;
    const int m_blk = blockIdx.x * BM;
    const int kb0 = blockIdx.z * KLEN;
    const int lm = lane & 15, lq = lane >> 4;
    const int sr = lane >> 2, sc = (lane & 3) << 3;
    const int f = flag[0];

    {   // conv weights/bias for this block's d-slice -> LDS
#pragma unroll
        for (int k = 0; k < 4; ++k) cws[tid * 4 + k] = rdf(cw, (size_t)(kb0 + tid) * 4 + k, f);
        cbs[tid] = rdf(cb, kb0 + tid, f);
    }
    __syncthreads();  // cws/cbs visible before any A-stage

    f32x4 acc[MT][NT];
#pragma unroll
    for (int i = 0; i < MT; ++i)
#pragma unroll
        for (int j = 0; j < NT; ++j) acc[i][j] = (f32x4){0.f, 0.f, 0.f, 0.f};

    const int arow = tid >> 3;          // 0..31: output t-row
    const int ag = (tid & 7) << 3;      // 0..56: d-offset within the 64-k step
    const int trow = m_blk + arow;

    auto bstage = [&](int buf, int kb) {
#pragma unroll
        for (int cch = 0; cch < 2; ++cch)
#pragma unroll
            for (int i = 0; i < BN / 64; ++i) {
                int row = i * 64 + w * 16;
                gload16(Bt + (size_t)(row + sr) * K + kb + cch * 32 + sc,
                        &Bs[buf][cch * BN * 32 + row * 32]);
            }
    };
    auto astage = [&](int buf, int kb) {   // covers the full 64-k step
        const int d = kb + ag;
        const int dl = kb - kb0 + ag;
        bf16x8 xv[4];
#pragma unroll
        for (int kk = 0; kk < 4; ++kk) {
            bf16x8 zz = {0, 0, 0, 0, 0, 0, 0, 0};
            int tt = trow + kk - 3;
            xv[kk] = (tt >= 0) ? *(const bf16x8*)(xz + (size_t)tt * 4096 + d) : zz;
        }
        bf16x8 rv;
#pragma unroll
        for (int j = 0; j < 8; ++j) {
            f32x4 wv = *(const f32x4*)(cws + (dl + j) * 4);
            float a = cbs[dl + j];
#pragma unroll
            for (int kk = 0; kk < 4; ++kk) a += b2f((u16)xv[kk][j]) * wv[kk];
            rv[j] = (short)f2b(a * fsig(a));
        }
        *(bf16x8*)(&As[buf][(ag >> 5) * BM * 32 + arow * 32 + (ag & 31)]) = rv;
        *(bf16x8*)(xconv + (size_t)trow * 2048 + d) = rv;
    };
    auto compute = [&](int buf) {
#pragma unroll
        for (int cch = 0; cch < 2; ++cch) {
            bf16x8 af[MT], bf[NT];
#pragma unroll
            for (int tm = 0; tm < MT; ++tm)
                af[tm] = *(const bf16x8*)(&As[buf][cch * BM * 32 +
                                                   (wm * 16 * MT + tm * 16 + lm) * 32 + lq * 8]);
#pragma unroll
            for (int tn = 0; tn < NT; ++tn)
                bf[tn] = *(const bf16x8*)(&Bs[buf][cch * BN * 32 +
                                                   (wn * 16 * NT + tn * 16 + lm) * 32 + lq * 8]);
#pragma unroll
            for (int tm = 0; tm < MT; ++tm)
#pragma unroll
                for (int tn = 0; tn < NT; ++tn)
                    acc[tm][tn] = __builtin_amdgcn_mfma_f32_16x16x32_bf16(af[tm], bf[tn],
                                                                          acc[tm][tn], 0, 0, 0);
        }
    };

    bstage(0, kb0);
    astage(0, kb0);
    __syncthreads();
    int cur = 0;
    for (int kb = kb0 + 64; kb < kb0 + KLEN; kb += 64) {
        bstage(cur ^ 1, kb);       // async loads first (in flight during A VALU + MFMA)
        astage(cur ^ 1, kb);
        compute(cur);
        __syncthreads();
        cur ^= 1;
    }
    compute(cur);

#pragma unroll
    for (int tm = 0; tm < MT; ++tm)
#pragma unroll
        for (int tn = 0; tn < NT; ++tn)
#pragma unroll
            for (int r = 0; r < 4; ++r) {
                int row = m_blk + wm * 16 * MT + tm * 16 + lq * 4 + r;
                int col = wn * 64 + tn * 16 + lm;
                parts[(size_t)blockIdx.z * 131072 + (size_t)row * 128 + col] = acc[tm][tn][r];
            }
}

// ---- in-block delta tile: dlt[32 t][128 d] = softplus(bf16(sum parts dt-cols) @ W_dt_t + b) ----
__device__ __forceinline__ void delta_tile(const float* __restrict__ parts,
                                           const u16* __restrict__ Wdt,  // W_dt_t [2048,64]
                                           const void* __restrict__ bias,
                                           int f, int t0, int d0,
                                           u16* As2, u16* Bs2, float (*dlt)[128],
                                           int tid, int w, int lm, int lq, int sr, int sc) {
#pragma unroll
    for (int cch = 0; cch < 2; ++cch)
#pragma unroll
        for (int i = 0; i < 2; ++i) {
            int row = i * 64 + w * 16;
            gload16(Wdt + (size_t)(d0 + row + sr) * 64 + cch * 32 + sc,
                    Bs2 + cch * 4096 + row * 32);
        }
    {
        int arow = tid >> 3, acg = (tid & 7) << 3;
        f32x4 s0 = {0.f, 0.f, 0.f, 0.f}, s1 = {0.f, 0.f, 0.f, 0.f};
#pragma unroll
        for (int sl = 0; sl < NSL; ++sl) {
            const float* p = parts + (size_t)sl * 131072 + (size_t)(t0 + arow) * 128 + acg;
            s0 += *(const f32x4*)p;
            s1 += *(const f32x4*)(p + 4);
        }
        bf16x8 rv;
#pragma unroll
        for (int j = 0; j < 4; ++j) {
            rv[j] = (short)f2b(s0[j]);
            rv[4 + j] = (short)f2b(s1[j]);
        }
        *(bf16x8*)(As2 + (acg >> 5) * 1024 + arow * 32 + (acg & 31)) = rv;
    }
    __syncthreads();  // As2/Bs2 (and caller's BCs) ready

    f32x4 dacc[2][2];
#pragma unroll
    for (int i = 0; i < 2; ++i)
#pragma unroll
        for (int j = 0; j < 2; ++j) dacc[i][j] = (f32x4){0.f, 0.f, 0.f, 0.f};
#pragma unroll
    for (int cch = 0; cch < 2; ++cch) {
        bf16x8 af[2], bf[2];
#pragma unroll
        for (int tm = 0; tm < 2; ++tm)
            af[tm] = *(const bf16x8*)(As2 + cch * 1024 + (tm * 16 + lm) * 32 + lq * 8);
#pragma unroll
        for (int tn = 0; tn < 2; ++tn)
            bf[tn] = *(const bf16x8*)(Bs2 + cch * 4096 + (w * 32 + tn * 16 + lm) * 32 + lq * 8);
#pragma unroll
        for (int tm = 0; tm < 2; ++tm)
#pragma unroll
            for (int tn = 0; tn < 2; ++tn)
                dacc[tm][tn] = __builtin_amdgcn_mfma_f32_16x16x32_bf16(af[tm], bf[tn],
                                                                       dacc[tm][tn], 0, 0, 0);
    }
#pragma unroll
    for (int tm = 0; tm < 2; ++tm)
#pragma unroll
        for (int tn = 0; tn < 2; ++tn)
#pragma unroll
            for (int r = 0; r < 4; ++r) {
                int row = tm * 16 + lq * 4 + r;
                int col = w * 32 + tn * 16 + lm;
                float b = rdf(bias, d0 + col, f);
                float t2 = dacc[tm][tn][r] + b;
                dlt[row][col] = fmaxf(t2, 0.f) + __logf(1.f + __expf(-fabsf(t2)));
            }
    __syncthreads();  // dlt ready
}

// ---------------- scan1: delta in-block; local scan; PERSIST dlt(fp32)+BC sums for scan3 ------
__global__ __launch_bounds__(256) void scan1_k(const u16* __restrict__ xc,
                                               const float* __restrict__ parts,
                                               const u16* __restrict__ Wdt,
                                               const void* __restrict__ bias,
                                               const void* __restrict__ A_log,
                                               float* __restrict__ Acar,
                                               float* __restrict__ Bcar,
                                               float* __restrict__ deltag,
                                               float* __restrict__ bcg,
                                               const int* __restrict__ flag) {
    __shared__ __align__(16) u16 As2[2 * 32 * 32];    // 4 KB
    __shared__ __align__(16) u16 Bs2[2 * 128 * 32];   // 16 KB
    __shared__ __align__(16) float dlt[32][128];      // 16 KB
    __shared__ __align__(16) float BCs[32][32];       // 4 KB
    const int f = *flag;
    const int tid = threadIdx.x, b = blockIdx.x;
    const int w = tid >> 6, lane = tid & 63;
    const int lm = lane & 15, lq = lane >> 4;
    const int sr = lane >> 2, sc = (lane & 3) << 3;
    const int c = b >> 4, dblk = b & 15;
    const int d0 = dblk * 128;
    const int t0 = c * 32;
    {
        int idx = tid * 4;
        int tl = idx >> 5, col = idx & 31;
        f32x4 s = {0.f, 0.f, 0.f, 0.f};
#pragma unroll
        for (int sl = 0; sl < NSL; ++sl)
            s += *(const f32x4*)(parts + (size_t)sl * 131072 + (size_t)(t0 + tl) * 128 + 64 + col);
        *(f32x4*)&BCs[tl][col] = s;
    }
    delta_tile(parts, Wdt, bias, f, t0, d0, As2, Bs2, dlt, tid, w, lm, lq, sr, sc);

    // persist dlt fp32 (scan3 re-reads instead of re-staging parts + MFMAs)
#pragma unroll
    for (int k = 0; k < 4; ++k) {
        int kk = tid + k * 256;                  // 0..1023 over 32x(128/4)
        int row = kk >> 5, col4 = (kk & 31) << 2;
        *(f32x4*)(deltag + (size_t)(t0 + row) * 2048 + d0 + col4) = *(const f32x4*)&dlt[row][col4];
    }
    // persist BC sums once per chunk (identical across the 16 dblk blocks)
    if (dblk == 0) {
        int idx = tid * 4;
        int tl = idx >> 5, col = idx & 31;
        *(f32x4*)(bcg + c * 1024 + tl * 32 + col) = *(const f32x4*)&BCs[tl][col];
    }

    const int dl = tid >> 1, nh = tid & 1;
    const int d = d0 + dl, n0 = nh << 3;
    float A[8], P[8], h[8];
#pragma unroll
    for (int j = 0; j < 8; ++j) {
        A[j] = -__expf(rdf(A_log, d * 16 + n0 + j, f));
        P[j] = 1.f;
        h[j] = 0.f;
    }
#pragma unroll 4
    for (int i = 0; i < 32; ++i) {
        int t = t0 + i;
        float de = dlt[i][dl];
        float dBu = de * b2f(xc[t * 2048 + d]);
        f32x4 Bv0 = *(const f32x4*)&BCs[i][n0];
        f32x4 Bv1 = *(const f32x4*)&BCs[i][n0 + 4];
#pragma unroll
        for (int j = 0; j < 8; ++j) {
            float Bv = (j < 4) ? Bv0[j & 3] : Bv1[j & 3];
            float a = __expf(de * A[j]);
            h[j] = a * h[j] + Bv * dBu;
            P[j] *= a;
        }
    }
    f32x4 pa0 = {P[0], P[1], P[2], P[3]}, pa1 = {P[4], P[5], P[6], P[7]};
    f32x4 hb0 = {h[0], h[1], h[2], h[3]}, hb1 = {h[4], h[5], h[6], h[7]};
    size_t base = (size_t)c * 32768 + d * 16 + n0;
    *(f32x4*)(Acar + base) = pa0;
    *(f32x4*)(Acar + base + 4) = pa1;
    *(f32x4*)(Bcar + base) = hb0;
    *(f32x4*)(Bcar + base + 4) = hb1;
}

// ---------------- scan3: load persisted dlt/BCs; inline lookback over raw carries -------------
__global__ __launch_bounds__(256) void scan3_k(const u16* __restrict__ xc,
                                               const float* __restrict__ deltag,
                                               const float* __restrict__ bcg,
                                               const u16* __restrict__ xz,
                                               const void* __restrict__ A_log,
                                               const void* __restrict__ Dvp,
                                               const float* __restrict__ Acar,
                                               const float* __restrict__ Bcar,
                                               u16* __restrict__ yg,
                                               const int* __restrict__ flag) {
    __shared__ __align__(16) float dlt[32][128];      // 16 KB
    __shared__ __align__(16) float BCs[32][32];       // 4 KB
    const int f = *flag;
    const int tid = threadIdx.x, b = blockIdx.x;
    const int c = b >> 4;
    const int d0 = (b & 15) * 128;
    const int t0 = c * 32;
    {
        int idx = tid * 4;
        int tl = idx >> 5, col = idx & 31;
        *(f32x4*)&BCs[tl][col] = *(const f32x4*)(bcg + c * 1024 + tl * 32 + col);
    }
#pragma unroll
    for (int k = 0; k < 4; ++k) {
        int kk = tid + k * 256;
        int row = kk >> 5, col4 = (kk & 31) << 2;
        *(f32x4*)&dlt[row][col4] = *(const f32x4*)(deltag + (size_t)(t0 + row) * 2048 + d0 + col4);
    }
    __syncthreads();

    const int dl = tid >> 1, nh = tid & 1;
    const int d = d0 + dl, n0 = nh << 3;
    float A[8], h[8];
#pragma unroll
    for (int j = 0; j < 8; ++j) {
        A[j] = -__expf(rdf(A_log, d * 16 + n0 + j, f));
        h[j] = 0.f;
    }
    // inline lookback (replaces scan2): compose raw carries ascending
    for (int cc = 0; cc < c; ++cc) {
        size_t cb = (size_t)cc * 32768 + d * 16 + n0;
        f32x4 a0 = *(const f32x4*)(Acar + cb);
        f32x4 a1 = *(const f32x4*)(Acar + cb + 4);
        f32x4 b0 = *(const f32x4*)(Bcar + cb);
        f32x4 b1 = *(const f32x4*)(Bcar + cb + 4);
#pragma unroll
        for (int j = 0; j < 4; ++j) {
            h[j] = a0[j] * h[j] + b0[j];
            h[4 + j] = a1[j] * h[4 + j] + b1[j];
        }
    }

    float Dd = rdf(Dvp, d, f);
#pragma unroll 4
    for (int i = 0; i < 32; ++i) {
        int t = t0 + i;
        float de = dlt[i][dl];
        float u = b2f(xc[t * 2048 + d]);
        float dBu = de * u;
        f32x4 Bv0 = *(const f32x4*)&BCs[i][n0];
        f32x4 Bv1 = *(const f32x4*)&BCs[i][n0 + 4];
        f32x4 Cv0 = *(const f32x4*)&BCs[i][16 + n0];
        f32x4 Cv1 = *(const f32x4*)&BCs[i][20 + n0];
        float p = 0.f;
#pragma unroll
        for (int j = 0; j < 8; ++j) {
            float Bv = (j < 4) ? Bv0[j & 3] : Bv1[j & 3];
            float Cv = (j < 4) ? Cv0[j & 3] : Cv1[j & 3];
            float a = __expf(de * A[j]);
            h[j] = a * h[j] + Bv * dBu;
            p += h[j] * Cv;
        }
        p += __shfl_xor(p, 1);  // combine the two n-halves (lanes 2k,2k+1 share d)
        if (nh == 0) {
            float r = b2f(xz[(size_t)t * 4096 + 2048 + d]);
            float yt = p + u * Dd;
            yg[t * 2048 + d] = f2b(yt * r * fsig(r));
        }
    }
}

// ---------------- fallback path (small ws): gemm3 -> delta, then monolithic scan --------------
__global__ __launch_bounds__(256) void gemm3_red_k(const float* __restrict__ parts,
                                                   const u16* __restrict__ Bt,   // W_dt_t [2048,64]
                                                   float* __restrict__ delta,
                                                   const void* __restrict__ bias,
                                                   const int* __restrict__ flag) {
    constexpr int MT = 2, NT = 2, BM = 64, BN = 64, K = 64;
    __shared__ __align__(16) u16 As[2 * BM * 32];
    __shared__ __align__(16) u16 Bs[2 * BN * 32];
    const int tid = threadIdx.x;
    const int w = tid >> 6, lane = tid & 63;
    const int wm = w & 1, wn = w >> 1;
    const int m_blk = blockIdx.x * BM, n_blk = blockIdx.y * BN;
    const int lm = lane & 15, lq = lane >> 4;
    const int sr = lane >> 2, sc = (lane & 3) << 3;
    const int f = flag[0];

    f32x4 acc[MT][NT];
#pragma unroll
    for (int i = 0; i < MT; ++i)
#pragma unroll
        for (int j = 0; j < NT; ++j) acc[i][j] = (f32x4){0.f, 0.f, 0.f, 0.f};

    const int arow = tid >> 2;
    const int acg = (tid & 3) << 3;

#pragma unroll
    for (int cch = 0; cch < 2; ++cch) {
        int row = w * 16;
        gload16(Bt + (size_t)(n_blk + row + sr) * K + cch * 32 + sc, &Bs[cch * BN * 32 + row * 32]);
    }
#pragma unroll
    for (int cch = 0; cch < 2; ++cch) {
        f32x4 s0 = {0.f, 0.f, 0.f, 0.f}, s1 = {0.f, 0.f, 0.f, 0.f};
#pragma unroll
        for (int sl = 0; sl < NSL; ++sl) {
            const float* p = parts + (size_t)sl * 131072 + (size_t)(m_blk + arow) * 128 + cch * 32 + acg;
            s0 += *(const f32x4*)p;
            s1 += *(const f32x4*)(p + 4);
        }
        bf16x8 rv;
#pragma unroll
        for (int j = 0; j < 4; ++j) {
            rv[j] = (short)f2b(s0[j]);
            rv[4 + j] = (short)f2b(s1[j]);
        }
        *(bf16x8*)(&As[cch * BM * 32 + arow * 32 + acg]) = rv;
    }
    __syncthreads();

#pragma unroll
    for (int cch = 0; cch < 2; ++cch) {
        bf16x8 af[MT], bf[NT];
#pragma unroll
        for (int tm = 0; tm < MT; ++tm)
            af[tm] = *(const bf16x8*)(&As[cch * BM * 32 + (wm * 32 + tm * 16 + lm) * 32 + lq * 8]);
#pragma unroll
        for (int tn = 0; tn < NT; ++tn)
            bf[tn] = *(const bf16x8*)(&Bs[cch * BN * 32 + (wn * 32 + tn * 16 + lm) * 32 + lq * 8]);
#pragma unroll
        for (int tm = 0; tm < MT; ++tm)
#pragma unroll
            for (int tn = 0; tn < NT; ++tn)
                acc[tm][tn] = __builtin_amdgcn_mfma_f32_16x16x32_bf16(af[tm], bf[tn],
                                                                      acc[tm][tn], 0, 0, 0);
    }

#pragma unroll
    for (int tm = 0; tm < MT; ++tm)
#pragma unroll
        for (int tn = 0; tn < NT; ++tn)
#pragma unroll
            for (int r = 0; r < 4; ++r) {
                int row = m_blk + wm * 32 + tm * 16 + lq * 4 + r;
                int col = n_blk + wn * 32 + tn * 16 + lm;
                float b = rdf(bias, col, f);
                float t2 = acc[tm][tn][r] + b;
                float sp = fmaxf(t2, 0.f) + __logf(1.f + __expf(-fabsf(t2)));
                delta[(size_t)row * 2048 + col] = sp;
            }
}

__global__ __launch_bounds__(256) void scan_k(const float* __restrict__ delta,
                                              const u16* __restrict__ xc,
                                              const float* __restrict__ parts,
                                              const u16* __restrict__ xz,
                                              const void* __restrict__ A_log,
                                              const void* __restrict__ Dvp,
                                              u16* __restrict__ yg,
                                              const int* __restrict__ flag) {
    int f = *flag;
    int g = blockIdx.x * 256 + threadIdx.x;
    int d = g >> 4, n = g & 15;
    float A = -__expf(rdf(A_log, d * 16 + n, f));
    float Dd = rdf(Dvp, d, f);
    float h = 0.f;
    for (int t = 0; t < LSEQ; ++t) {
        float de = delta[t * 2048 + d];
        float u = b2f(xc[t * 2048 + d]);
        float Bv = 0.f, Cv = 0.f;
#pragma unroll
        for (int sl = 0; sl < NSL; ++sl) {
            Bv += parts[(size_t)sl * 131072 + (size_t)t * 128 + 64 + n];
            Cv += parts[(size_t)sl * 131072 + (size_t)t * 128 + 80 + n];
        }
        h = __expf(de * A) * h + (de * Bv) * u;
        float p = h * Cv;
        p += __shfl_xor(p, 1);
        p += __shfl_xor(p, 2);
        p += __shfl_xor(p, 4);
        p += __shfl_xor(p, 8);
        if (n == 0) {
            float r = b2f(xz[(size_t)t * 4096 + 2048 + d]);
            float yt = p + u * Dd;
            yg[t * 2048 + d] = f2b(yt * r * fsig(r));
        }
    }
}

extern "C" void kernel_launch(void* const* d_in, const int* in_sizes, int n_in,
                              void* d_out, int out_size, void* d_ws, size_t ws_size,
                              hipStream_t stream) {
    const void* x      = d_in[0];
    const void* W_in   = d_in[1];
    const void* conv_w = d_in[2];
    const void* conv_b = d_in[3];
    const void* W_x    = d_in[4];
    const void* W_dt   = d_in[5];
    const void* b_dt   = d_in[6];
    const void* A_log  = d_in[7];
    const void* Dv     = d_in[8];
    const void* W_out  = d_in[9];

    char* ws = (char*)d_ws;
    u16*   xz     = (u16*)(ws);               // [1024,4096] bf16 = 8388608       -> 8388608
    u16*   xconv  = (u16*)(ws + 8388608);     // [1024,2048] bf16 = 4194304       -> 12582912
    float* parts  = (float*)(ws + 12582912);  // [8,1024,128] fp32 = 4194304      -> 16777216
    u16*   W_in_t = (u16*)(ws + 16777216);    // W_in^T [4096,1024] = 8388608     -> 25165824
    u16*   yg     = (u16*)(ws + 25165824);    // [1024,2048] bf16 = 4194304       -> 29360128
    u16*   xb     = (u16*)(ws + 25165824);    // alias yg: x bf16, gemm1 only
    u16*   W_x_t  = (u16*)(ws + 29360128);    // W_x^T padded [128,2048] = 524288 -> 29884416
    u16*   W_dt_t = (u16*)(ws + 29884416);    // W_dt^T [2048,64] = 262144        -> 30146560
    u16*   W_out_t= (u16*)(ws + 30146560);    // W_out^T [1024,2048] = 4194304    -> 34340864
    int*   flag   = (int*)(ws + 34340864);    // 4 B (pad to 34340992)
    float* Acar   = (float*)(ws + 34340992);  // 4194304 -> 38535296
    float* Bcar   = (float*)(ws + 38535296);  // 4194304 -> 42729600
    float* deltag = (float*)(ws + 42729600);  // [1024,2048] fp32 = 8388608 -> 51118208
    float* bcg    = (float*)(ws + 51118208);  // [32,1024] fp32 = 131072 -> 51249280
    float* dfb    = (float*)(ws + 34340992);  // fallback delta alias (Acar+Bcar region)
    const bool chunked_ok = (ws_size >= 51249280);

    // 0) prep: detect + x->bf16 + W_in^T only (other transposes ride gemm1)
    prep_k<<<5120, 256, 0, stream>>>(x, W_in, xb, W_in_t, flag);
    // 1) gemm1 FAT: xz = xb @ W_in^T (512 gemm blocks = 2/CU) + 2432 transpose riders
    gemm1_fat_k<<<dim3(16, 184), 256, 0, stream>>>(xb, W_in_t, xz,
                                                   W_out, W_x, W_dt,
                                                   W_out_t, W_x_t, W_dt_t, flag);
    // 2+3) x_dbl partials = silu(conv(x_in)) @ W_x^T; BM=32, 8 k-slices ->
    //      256 blocks = 1/CU (R13 was 128 = 0.5/CU), NSL stays 8 (scan1 untouched)
    gemm2_conv_k<<<dim3(32, 1, 8), 256, 0, stream>>>(xz, W_x_t, parts, xconv,
                                                     conv_w, conv_b, flag);

    // 4+5) scan: 2 dispatches. scan1 computes delta in-block + persists dlt/BC sums;
    //      scan3 reloads them and inlines the lookback (dispatch boundary = the sync).
    if (chunked_ok) {
        scan1_k<<<512, 256, 0, stream>>>(xconv, parts, W_dt_t, b_dt, A_log, Acar, Bcar,
                                         deltag, bcg, flag);
        scan3_k<<<512, 256, 0, stream>>>(xconv, deltag, bcg, xz, A_log, Dv,
                                         Acar, Bcar, yg, flag);
    } else {
        gemm3_red_k<<<dim3(16, 32), 256, 0, stream>>>(parts, W_dt_t, dfb, b_dt, flag);
        scan_k<<<128, 256, 0, stream>>>(dfb, xconv, parts, xz, A_log, Dv, yg, flag);
    }

    // 6) out = yg @ W_out  [1024,1024]  (64x64 tiles, 256 blocks; R13 config)
    gemm_bt<2, 2, 2><<<dim3(16, 16), 256, 0, stream>>>(yg, W_out_t, d_out,
                                                       1024, 1024, 2048, flag);
}

// Round 16
// 197.038 us; speedup vs baseline: 1.0304x; 1.0058x over previous
//
#include <hip/hip_runtime.h>

typedef unsigned short u16;
typedef unsigned int u32;
typedef __attribute__((ext_vector_type(8))) short bf16x8;
typedef __attribute__((ext_vector_type(4))) float f32x4;

#define LSEQ 1024
#define NSL 8  // k-slices for gemm2 / parts

__device__ __forceinline__ float b2f(u16 v) { return __uint_as_float(((u32)v) << 16); }
__device__ __forceinline__ u16 f2b(float f) {
    u32 x = __float_as_uint(f);
    return (u16)((x + 0x7fffu + ((x >> 16) & 1u)) >> 16);
}
__device__ __forceinline__ float rdf(const void* p, size_t i, int f) {
    return f ? b2f(((const u16*)p)[i]) : ((const float*)p)[i];
}
__device__ __forceinline__ float fsig(float x) {
    return __builtin_amdgcn_rcpf(1.f + __expf(-x));
}

typedef const __attribute__((address_space(1))) u32* gp_t;
typedef __attribute__((address_space(3))) u32* lp_t;
__device__ __forceinline__ void gload16(const u16* g, u16* lds_wave_base) {
    __builtin_amdgcn_global_load_lds((gp_t)g, (lp_t)lds_wave_base, 16, 0, 0);
}

// shared transpose-tile body: dst[Cp,R] = src[R,Cn]^T (zero-padded cols >= Cn)
__device__ __forceinline__ void transpose_tile(const void* src, u16* dst, int R, int Cn,
                                               int br, int bc, int f, u16 (*tile)[36]) {
    int r0 = br * 32, c0 = bc * 32;
    {
        int ty = threadIdx.x >> 3, tx4 = (threadIdx.x & 7) << 2;
        u16 o0 = 0, o1 = 0, o2 = 0, o3 = 0;
        if (c0 + tx4 < Cn) {
            size_t off = (size_t)(r0 + ty) * Cn + c0 + tx4;
            if (f) {
                ushort4 u = *(const ushort4*)((const u16*)src + off);
                o0 = u.x; o1 = u.y; o2 = u.z; o3 = u.w;
            } else {
                float4 v = *(const float4*)((const float*)src + off);
                o0 = f2b(v.x); o1 = f2b(v.y); o2 = f2b(v.z); o3 = f2b(v.w);
            }
        }
        *(ushort4*)(&tile[ty][tx4]) = make_ushort4(o0, o1, o2, o3);
    }
    __syncthreads();
    {
        int cc = threadIdx.x >> 3, r4 = (threadIdx.x & 7) << 2;
        ushort4 o = make_ushort4(tile[r4][cc], tile[r4 + 1][cc], tile[r4 + 2][cc], tile[r4 + 3][cc]);
        *(ushort4*)(dst + (size_t)(c0 + cc) * R + r0 + r4) = o;
    }
}

// ---------------- prep: dtype detect + x->bf16 + W_in^T ONLY (other transposes ride gemm1) ----
__global__ __launch_bounds__(256) void prep_k(const void* __restrict__ x,
                                              const void* __restrict__ W_in,
                                              u16* __restrict__ xb,
                                              u16* __restrict__ W_in_t,
                                              int* __restrict__ flag) {
    __shared__ int cnt;
    __shared__ __align__(8) u16 tile[32][36];
    if (threadIdx.x == 0) cnt = 0;
    __syncthreads();
    const u16* xu = (const u16*)x;
    int c = 0;
#pragma unroll
    for (int j = 0; j < 8; ++j) {
        u16 u = xu[threadIdx.x * 8 + j];
        int e = (u >> 7) & 0xFF;
        c += (e == 0 || (e >= 100 && e <= 140)) ? 1 : 0;
    }
    atomicAdd(&cnt, c);
    __syncthreads();
    const int f = (cnt >= 1638) ? 1 : 0;
    if (blockIdx.x == 0 && threadIdx.x == 0) *flag = f;

    int blk = blockIdx.x;
    if (blk < 1024) {  // x -> bf16, 4 elems/thread
        int i = (blk * 256 + threadIdx.x) * 4;
        ushort4 o;
        if (f) {
            o = *(const ushort4*)(xu + i);
        } else {
            float4 v = *(const float4*)((const float*)x + i);
            o = make_ushort4(f2b(v.x), f2b(v.y), f2b(v.z), f2b(v.w));
        }
        *(ushort4*)(xb + i) = o;
        return;
    }
    blk -= 1024;   // 0..4095: W_in [1024,4096] -> W_in_t, nbc=128
    transpose_tile(W_in, W_in_t, 1024, 4096, blk / 128, blk % 128, f, tile);
}

// ---------------- gemm1 FAT: xz = xb @ W_in_t^T  +  rider blocks do W_out/W_x/W_dt transposes --
// grid (16, 32+152): blockIdx.y < 32 -> 64x128 gemm tile; else rider id in [0,2432).
__global__ __launch_bounds__(256) void gemm1_fat_k(const u16* __restrict__ A,
                                                   const u16* __restrict__ Bt,
                                                   u16* __restrict__ C,
                                                   const void* __restrict__ W_out,
                                                   const void* __restrict__ W_x,
                                                   const void* __restrict__ W_dt,
                                                   u16* __restrict__ W_out_t,
                                                   u16* __restrict__ W_x_t,
                                                   u16* __restrict__ W_dt_t,
                                                   const int* __restrict__ flag) {
    constexpr int MT = 2, NT = 4, BM = 64, BN = 128, N = 4096, K = 1024;
    __shared__ __align__(16) u16 As[2][2 * BM * 32];
    __shared__ __align__(16) u16 Bs[2][2 * BN * 32];
    __shared__ __align__(8) u16 tile[32][36];
    if (blockIdx.y >= 32) {  // ---- transpose rider ----
        int id = (blockIdx.y - 32) * 16 + blockIdx.x;  // 0..2431
        const int f = flag[0];
        const void* src; u16* dst; int R, Cn, nbc, t;
        if (id < 2048)      { src = W_out; dst = W_out_t; R = 2048; Cn = 1024; nbc = 32; t = id; }
        else if (id < 2304) { src = W_x;   dst = W_x_t;   R = 2048; Cn = 96;   nbc = 4;  t = id - 2048; }
        else                { src = W_dt;  dst = W_dt_t;  R = 64;   Cn = 2048; nbc = 64; t = id - 2304; }
        transpose_tile(src, dst, R, Cn, t / nbc, t % nbc, f, tile);
        return;
    }
    const int tid = threadIdx.x;
    const int w = tid >> 6, lane = tid & 63;
    const int wm = w & 1, wn = w >> 1;
    const int m_blk = blockIdx.x * BM, n_blk = blockIdx.y * BN;
    const int lm = lane & 15, lq = lane >> 4;
    const int sr = lane >> 2, sc = (lane & 3) << 3;

    f32x4 acc[MT][NT];
#pragma unroll
    for (int i = 0; i < MT; ++i)
#pragma unroll
        for (int j = 0; j < NT; ++j) acc[i][j] = (f32x4){0.f, 0.f, 0.f, 0.f};

    auto stage = [&](int buf, int kb) {
#pragma unroll
        for (int cch = 0; cch < 2; ++cch) {
#pragma unroll
            for (int i = 0; i < BM / 64; ++i) {
                int row = i * 64 + w * 16;
                gload16(A + (size_t)(m_blk + row + sr) * K + kb + cch * 32 + sc,
                        &As[buf][cch * BM * 32 + row * 32]);
            }
#pragma unroll
            for (int i = 0; i < BN / 64; ++i) {
                int row = i * 64 + w * 16;
                gload16(Bt + (size_t)(n_blk + row + sr) * K + kb + cch * 32 + sc,
                        &Bs[buf][cch * BN * 32 + row * 32]);
            }
        }
    };
    auto compute = [&](int buf) {
#pragma unroll
        for (int cch = 0; cch < 2; ++cch) {
            bf16x8 af[MT], bf[NT];
#pragma unroll
            for (int tm = 0; tm < MT; ++tm)
                af[tm] = *(const bf16x8*)(&As[buf][cch * BM * 32 +
                                                   (wm * 16 * MT + tm * 16 + lm) * 32 + lq * 8]);
#pragma unroll
            for (int tn = 0; tn < NT; ++tn)
                bf[tn] = *(const bf16x8*)(&Bs[buf][cch * BN * 32 +
                                                   (wn * 16 * NT + tn * 16 + lm) * 32 + lq * 8]);
#pragma unroll
            for (int tm = 0; tm < MT; ++tm)
#pragma unroll
                for (int tn = 0; tn < NT; ++tn)
                    acc[tm][tn] = __builtin_amdgcn_mfma_f32_16x16x32_bf16(af[tm], bf[tn],
                                                                          acc[tm][tn], 0, 0, 0);
        }
    };

    stage(0, 0);
    __syncthreads();
    int cur = 0;
    for (int kb = 64; kb < K; kb += 64) {
        stage(cur ^ 1, kb);
        compute(cur);
        __syncthreads();
        cur ^= 1;
    }
    compute(cur);

#pragma unroll
    for (int tm = 0; tm < MT; ++tm)
#pragma unroll
        for (int tn = 0; tn < NT; ++tn)
#pragma unroll
            for (int r = 0; r < 4; ++r) {
                int row = m_blk + wm * 16 * MT + tm * 16 + lq * 4 + r;
                int col = n_blk + wn * 16 * NT + tn * 16 + lm;
                C[(size_t)row * N + col] = f2b(acc[tm][tn][r]);
            }
}

// ---------------- GEMM, B transposed (gemm4): C[M,N] = A[M,K] * Bt[N,K]^T ----------------
// BK=64 dbuf, guarded staging.
template <int MT, int NT, int OUT_MODE>
__global__ __launch_bounds__(256) void gemm_bt(const u16* __restrict__ A,
                                               const u16* __restrict__ Bt,
                                               void* __restrict__ C,
                                               int M, int N, int K,
                                               const int* __restrict__ flag) {
    constexpr int BM = 32 * MT, BN = 32 * NT;
    __shared__ __align__(16) u16 As[2][2 * BM * 32];
    __shared__ __align__(16) u16 Bs[2][2 * BN * 32];
    const int tid = threadIdx.x;
    const int w = tid >> 6, lane = tid & 63;
    const int wm = w & 1, wn = w >> 1;
    const int m_blk = blockIdx.x * BM, n_blk = blockIdx.y * BN;
    const int lm = lane & 15, lq = lane >> 4;
    const int sr = lane >> 2, sc = (lane & 3) << 3;
    const int f = (OUT_MODE == 2) ? flag[0] : 0;

    f32x4 acc[MT][NT];
#pragma unroll
    for (int i = 0; i < MT; ++i)
#pragma unroll
        for (int j = 0; j < NT; ++j) acc[i][j] = (f32x4){0.f, 0.f, 0.f, 0.f};

    auto stage = [&](int buf, int kb) {
#pragma unroll
        for (int cch = 0; cch < 2; ++cch) {
#pragma unroll
            for (int i = 0; i < (BM + 63) / 64; ++i) {
                int row = i * 64 + w * 16;
                if (row < BM)
                    gload16(A + (size_t)(m_blk + row + sr) * K + kb + cch * 32 + sc,
                            &As[buf][cch * BM * 32 + row * 32]);
            }
#pragma unroll
            for (int i = 0; i < (BN + 63) / 64; ++i) {
                int row = i * 64 + w * 16;
                if (row < BN)
                    gload16(Bt + (size_t)(n_blk + row + sr) * K + kb + cch * 32 + sc,
                            &Bs[buf][cch * BN * 32 + row * 32]);
            }
        }
    };
    auto compute = [&](int buf) {
#pragma unroll
        for (int cch = 0; cch < 2; ++cch) {
            bf16x8 af[MT], bf[NT];
#pragma unroll
            for (int tm = 0; tm < MT; ++tm)
                af[tm] = *(const bf16x8*)(&As[buf][cch * BM * 32 +
                                                   (wm * 16 * MT + tm * 16 + lm) * 32 + lq * 8]);
#pragma unroll
            for (int tn = 0; tn < NT; ++tn)
                bf[tn] = *(const bf16x8*)(&Bs[buf][cch * BN * 32 +
                                                   (wn * 16 * NT + tn * 16 + lm) * 32 + lq * 8]);
#pragma unroll
            for (int tm = 0; tm < MT; ++tm)
#pragma unroll
                for (int tn = 0; tn < NT; ++tn)
                    acc[tm][tn] = __builtin_amdgcn_mfma_f32_16x16x32_bf16(af[tm], bf[tn],
                                                                          acc[tm][tn], 0, 0, 0);
        }
    };

    stage(0, 0);
    __syncthreads();
    int cur = 0;
    for (int kb = 64; kb < K; kb += 64) {
        stage(cur ^ 1, kb);
        compute(cur);
        __syncthreads();
        cur ^= 1;
    }
    compute(cur);

#pragma unroll
    for (int tm = 0; tm < MT; ++tm)
#pragma unroll
        for (int tn = 0; tn < NT; ++tn)
#pragma unroll
            for (int r = 0; r < 4; ++r) {
                int row = m_blk + wm * 16 * MT + tm * 16 + lq * 4 + r;
                int col = n_blk + wn * 16 * NT + tn * 16 + lm;
                float v = acc[tm][tn][r];
                if (OUT_MODE == 1) {
                    ((u16*)C)[(size_t)row * N + col] = f2b(v);
                } else {  // 2: dual
                    if (f) ((u16*)C)[(size_t)row * N + col] = f2b(v);
                    else   ((float*)C)[(size_t)row * N + col] = v;
                }
            }
}

// ---------------- gemm2 fused: A = silu(causal_dw_conv(xz[:, :2048])) computed in-staging ----
// BM=32, NT=2 (BN=64 n-split), 8 k-slices -> grid (32,2,8) = 512 blocks = 2/CU.
// NSL stays 8 (scan1 untouched). Conv A-stage duplicated across the 2 n-halves (~1.2us);
// each parts element still written by exactly one block in identical k-order -> bitwise-same.
// xconv written twice with identical bytes (benign).
__global__ __launch_bounds__(256) void gemm2_conv_k(const u16* __restrict__ xz,
                                                    const u16* __restrict__ Bt,   // W_x_t [128,2048]
                                                    float* __restrict__ parts,
                                                    u16* __restrict__ xconv,
                                                    const void* __restrict__ cw,
                                                    const void* __restrict__ cb,
                                                    const int* __restrict__ flag) {
    constexpr int MT = 1, NT = 2;
    constexpr int BM = 32, BN = 64, K = 2048, KLEN = 256;
    __shared__ __align__(16) u16 As[2][2 * BM * 32];
    __shared__ __align__(16) u16 Bs[2][2 * BN * 32];
    __shared__ __align__(16) float cws[KLEN * 4];
    __shared__ float cbs[KLEN];
    const int tid = threadIdx.x;
    const int w = tid >> 6, lane = tid & 63;
    const int wm = w & 1, wn = w >> 1;
    const int m_blk = blockIdx.x * BM;
    const int n_blk = blockIdx.y * BN;          // 0 or 64
    const int kb0 = blockIdx.z * KLEN;
    const int lm = lane & 15, lq = lane >> 4;
    const int sr = lane >> 2, sc = (lane & 3) << 3;
    const int f = flag[0];

    {   // conv weights/bias for this block's d-slice -> LDS
#pragma unroll
        for (int k = 0; k < 4; ++k) cws[tid * 4 + k] = rdf(cw, (size_t)(kb0 + tid) * 4 + k, f);
        cbs[tid] = rdf(cb, kb0 + tid, f);
    }
    __syncthreads();  // cws/cbs visible before any A-stage

    f32x4 acc[MT][NT];
#pragma unroll
    for (int i = 0; i < MT; ++i)
#pragma unroll
        for (int j = 0; j < NT; ++j) acc[i][j] = (f32x4){0.f, 0.f, 0.f, 0.f};

    const int arow = tid >> 3;          // 0..31: output t-row
    const int ag = (tid & 7) << 3;      // 0..56: d-offset within the 64-k step
    const int trow = m_blk + arow;

    auto bstage = [&](int buf, int kb) {
#pragma unroll
        for (int cch = 0; cch < 2; ++cch) {
            int row = w * 16;   // BN=64: one 64-row pass, 4 waves x 16 rows
            gload16(Bt + (size_t)(n_blk + row + sr) * K + kb + cch * 32 + sc,
                    &Bs[buf][cch * BN * 32 + row * 32]);
        }
    };
    auto astage = [&](int buf, int kb) {   // covers the full 64-k step
        const int d = kb + ag;
        const int dl = kb - kb0 + ag;
        bf16x8 xv[4];
#pragma unroll
        for (int kk = 0; kk < 4; ++kk) {
            bf16x8 zz = {0, 0, 0, 0, 0, 0, 0, 0};
            int tt = trow + kk - 3;
            xv[kk] = (tt >= 0) ? *(const bf16x8*)(xz + (size_t)tt * 4096 + d) : zz;
        }
        bf16x8 rv;
#pragma unroll
        for (int j = 0; j < 8; ++j) {
            f32x4 wv = *(const f32x4*)(cws + (dl + j) * 4);
            float a = cbs[dl + j];
#pragma unroll
            for (int kk = 0; kk < 4; ++kk) a += b2f((u16)xv[kk][j]) * wv[kk];
            rv[j] = (short)f2b(a * fsig(a));
        }
        *(bf16x8*)(&As[buf][(ag >> 5) * BM * 32 + arow * 32 + (ag & 31)]) = rv;
        *(bf16x8*)(xconv + (size_t)trow * 2048 + d) = rv;   // both n-halves write same bytes
    };
    auto compute = [&](int buf) {
#pragma unroll
        for (int cch = 0; cch < 2; ++cch) {
            bf16x8 af[MT], bf[NT];
#pragma unroll
            for (int tm = 0; tm < MT; ++tm)
                af[tm] = *(const bf16x8*)(&As[buf][cch * BM * 32 +
                                                   (wm * 16 * MT + tm * 16 + lm) * 32 + lq * 8]);
#pragma unroll
            for (int tn = 0; tn < NT; ++tn)
                bf[tn] = *(const bf16x8*)(&Bs[buf][cch * BN * 32 +
                                                   (wn * 16 * NT + tn * 16 + lm) * 32 + lq * 8]);
#pragma unroll
            for (int tm = 0; tm < MT; ++tm)
#pragma unroll
                for (int tn = 0; tn < NT; ++tn)
                    acc[tm][tn] = __builtin_amdgcn_mfma_f32_16x16x32_bf16(af[tm], bf[tn],
                                                                          acc[tm][tn], 0, 0, 0);
        }
    };

    bstage(0, kb0);
    astage(0, kb0);
    __syncthreads();
    int cur = 0;
    for (int kb = kb0 + 64; kb < kb0 + KLEN; kb += 64) {
        bstage(cur ^ 1, kb);       // async loads first (in flight during A VALU + MFMA)
        astage(cur ^ 1, kb);
        compute(cur);
        __syncthreads();
        cur ^= 1;
    }
    compute(cur);

#pragma unroll
    for (int tm = 0; tm < MT; ++tm)
#pragma unroll
        for (int tn = 0; tn < NT; ++tn)
#pragma unroll
            for (int r = 0; r < 4; ++r) {
                int row = m_blk + wm * 16 * MT + tm * 16 + lq * 4 + r;
                int col = n_blk + wn * 16 * NT + tn * 16 + lm;
                parts[(size_t)blockIdx.z * 131072 + (size_t)row * 128 + col] = acc[tm][tn][r];
            }
}

// ---- in-block delta tile: dlt[32 t][128 d] = softplus(bf16(sum parts dt-cols) @ W_dt_t + b) ----
__device__ __forceinline__ void delta_tile(const float* __restrict__ parts,
                                           const u16* __restrict__ Wdt,  // W_dt_t [2048,64]
                                           const void* __restrict__ bias,
                                           int f, int t0, int d0,
                                           u16* As2, u16* Bs2, float (*dlt)[128],
                                           int tid, int w, int lm, int lq, int sr, int sc) {
#pragma unroll
    for (int cch = 0; cch < 2; ++cch)
#pragma unroll
        for (int i = 0; i < 2; ++i) {
            int row = i * 64 + w * 16;
            gload16(Wdt + (size_t)(d0 + row + sr) * 64 + cch * 32 + sc,
                    Bs2 + cch * 4096 + row * 32);
        }
    {
        int arow = tid >> 3, acg = (tid & 7) << 3;
        f32x4 s0 = {0.f, 0.f, 0.f, 0.f}, s1 = {0.f, 0.f, 0.f, 0.f};
#pragma unroll
        for (int sl = 0; sl < NSL; ++sl) {
            const float* p = parts + (size_t)sl * 131072 + (size_t)(t0 + arow) * 128 + acg;
            s0 += *(const f32x4*)p;
            s1 += *(const f32x4*)(p + 4);
        }
        bf16x8 rv;
#pragma unroll
        for (int j = 0; j < 4; ++j) {
            rv[j] = (short)f2b(s0[j]);
            rv[4 + j] = (short)f2b(s1[j]);
        }
        *(bf16x8*)(As2 + (acg >> 5) * 1024 + arow * 32 + (acg & 31)) = rv;
    }
    __syncthreads();  // As2/Bs2 (and caller's BCs) ready

    f32x4 dacc[2][2];
#pragma unroll
    for (int i = 0; i < 2; ++i)
#pragma unroll
        for (int j = 0; j < 2; ++j) dacc[i][j] = (f32x4){0.f, 0.f, 0.f, 0.f};
#pragma unroll
    for (int cch = 0; cch < 2; ++cch) {
        bf16x8 af[2], bf[2];
#pragma unroll
        for (int tm = 0; tm < 2; ++tm)
            af[tm] = *(const bf16x8*)(As2 + cch * 1024 + (tm * 16 + lm) * 32 + lq * 8);
#pragma unroll
        for (int tn = 0; tn < 2; ++tn)
            bf[tn] = *(const bf16x8*)(Bs2 + cch * 4096 + (w * 32 + tn * 16 + lm) * 32 + lq * 8);
#pragma unroll
        for (int tm = 0; tm < 2; ++tm)
#pragma unroll
            for (int tn = 0; tn < 2; ++tn)
                dacc[tm][tn] = __builtin_amdgcn_mfma_f32_16x16x32_bf16(af[tm], bf[tn],
                                                                       dacc[tm][tn], 0, 0, 0);
    }
#pragma unroll
    for (int tm = 0; tm < 2; ++tm)
#pragma unroll
        for (int tn = 0; tn < 2; ++tn)
#pragma unroll
            for (int r = 0; r < 4; ++r) {
                int row = tm * 16 + lq * 4 + r;
                int col = w * 32 + tn * 16 + lm;
                float b = rdf(bias, d0 + col, f);
                float t2 = dacc[tm][tn][r] + b;
                dlt[row][col] = fmaxf(t2, 0.f) + __logf(1.f + __expf(-fabsf(t2)));
            }
    __syncthreads();  // dlt ready
}

// ---------------- scan1: delta in-block; local scan; PERSIST dlt(fp32)+BC sums for scan3 ------
__global__ __launch_bounds__(256) void scan1_k(const u16* __restrict__ xc,
                                               const float* __restrict__ parts,
                                               const u16* __restrict__ Wdt,
                                               const void* __restrict__ bias,
                                               const void* __restrict__ A_log,
                                               float* __restrict__ Acar,
                                               float* __restrict__ Bcar,
                                               float* __restrict__ deltag,
                                               float* __restrict__ bcg,
                                               const int* __restrict__ flag) {
    __shared__ __align__(16) u16 As2[2 * 32 * 32];    // 4 KB
    __shared__ __align__(16) u16 Bs2[2 * 128 * 32];   // 16 KB
    __shared__ __align__(16) float dlt[32][128];      // 16 KB
    __shared__ __align__(16) float BCs[32][32];       // 4 KB
    const int f = *flag;
    const int tid = threadIdx.x, b = blockIdx.x;
    const int w = tid >> 6, lane = tid & 63;
    const int lm = lane & 15, lq = lane >> 4;
    const int sr = lane >> 2, sc = (lane & 3) << 3;
    const int c = b >> 4, dblk = b & 15;
    const int d0 = dblk * 128;
    const int t0 = c * 32;
    {
        int idx = tid * 4;
        int tl = idx >> 5, col = idx & 31;
        f32x4 s = {0.f, 0.f, 0.f, 0.f};
#pragma unroll
        for (int sl = 0; sl < NSL; ++sl)
            s += *(const f32x4*)(parts + (size_t)sl * 131072 + (size_t)(t0 + tl) * 128 + 64 + col);
        *(f32x4*)&BCs[tl][col] = s;
    }
    delta_tile(parts, Wdt, bias, f, t0, d0, As2, Bs2, dlt, tid, w, lm, lq, sr, sc);

    // persist dlt fp32 (scan3 re-reads instead of re-staging parts + MFMAs)
#pragma unroll
    for (int k = 0; k < 4; ++k) {
        int kk = tid + k * 256;                  // 0..1023 over 32x(128/4)
        int row = kk >> 5, col4 = (kk & 31) << 2;
        *(f32x4*)(deltag + (size_t)(t0 + row) * 2048 + d0 + col4) = *(const f32x4*)&dlt[row][col4];
    }
    // persist BC sums once per chunk (identical across the 16 dblk blocks)
    if (dblk == 0) {
        int idx = tid * 4;
        int tl = idx >> 5, col = idx & 31;
        *(f32x4*)(bcg + c * 1024 + tl * 32 + col) = *(const f32x4*)&BCs[tl][col];
    }

    const int dl = tid >> 1, nh = tid & 1;
    const int d = d0 + dl, n0 = nh << 3;
    float A[8], P[8], h[8];
#pragma unroll
    for (int j = 0; j < 8; ++j) {
        A[j] = -__expf(rdf(A_log, d * 16 + n0 + j, f));
        P[j] = 1.f;
        h[j] = 0.f;
    }
#pragma unroll 4
    for (int i = 0; i < 32; ++i) {
        int t = t0 + i;
        float de = dlt[i][dl];
        float dBu = de * b2f(xc[t * 2048 + d]);
        f32x4 Bv0 = *(const f32x4*)&BCs[i][n0];
        f32x4 Bv1 = *(const f32x4*)&BCs[i][n0 + 4];
#pragma unroll
        for (int j = 0; j < 8; ++j) {
            float Bv = (j < 4) ? Bv0[j & 3] : Bv1[j & 3];
            float a = __expf(de * A[j]);
            h[j] = a * h[j] + Bv * dBu;
            P[j] *= a;
        }
    }
    f32x4 pa0 = {P[0], P[1], P[2], P[3]}, pa1 = {P[4], P[5], P[6], P[7]};
    f32x4 hb0 = {h[0], h[1], h[2], h[3]}, hb1 = {h[4], h[5], h[6], h[7]};
    size_t base = (size_t)c * 32768 + d * 16 + n0;
    *(f32x4*)(Acar + base) = pa0;
    *(f32x4*)(Acar + base + 4) = pa1;
    *(f32x4*)(Bcar + base) = hb0;
    *(f32x4*)(Bcar + base + 4) = hb1;
}

// ---------------- scan3: load persisted dlt/BCs; inline lookback over raw carries -------------
__global__ __launch_bounds__(256) void scan3_k(const u16* __restrict__ xc,
                                               const float* __restrict__ deltag,
                                               const float* __restrict__ bcg,
                                               const u16* __restrict__ xz,
                                               const void* __restrict__ A_log,
                                               const void* __restrict__ Dvp,
                                               const float* __restrict__ Acar,
                                               const float* __restrict__ Bcar,
                                               u16* __restrict__ yg,
                                               const int* __restrict__ flag) {
    __shared__ __align__(16) float dlt[32][128];      // 16 KB
    __shared__ __align__(16) float BCs[32][32];       // 4 KB
    const int f = *flag;
    const int tid = threadIdx.x, b = blockIdx.x;
    const int c = b >> 4;
    const int d0 = (b & 15) * 128;
    const int t0 = c * 32;
    {
        int idx = tid * 4;
        int tl = idx >> 5, col = idx & 31;
        *(f32x4*)&BCs[tl][col] = *(const f32x4*)(bcg + c * 1024 + tl * 32 + col);
    }
#pragma unroll
    for (int k = 0; k < 4; ++k) {
        int kk = tid + k * 256;
        int row = kk >> 5, col4 = (kk & 31) << 2;
        *(f32x4*)&dlt[row][col4] = *(const f32x4*)(deltag + (size_t)(t0 + row) * 2048 + d0 + col4);
    }
    __syncthreads();

    const int dl = tid >> 1, nh = tid & 1;
    const int d = d0 + dl, n0 = nh << 3;
    float A[8], h[8];
#pragma unroll
    for (int j = 0; j < 8; ++j) {
        A[j] = -__expf(rdf(A_log, d * 16 + n0 + j, f));
        h[j] = 0.f;
    }
    // inline lookback (replaces scan2): compose raw carries ascending
    for (int cc = 0; cc < c; ++cc) {
        size_t cb = (size_t)cc * 32768 + d * 16 + n0;
        f32x4 a0 = *(const f32x4*)(Acar + cb);
        f32x4 a1 = *(const f32x4*)(Acar + cb + 4);
        f32x4 b0 = *(const f32x4*)(Bcar + cb);
        f32x4 b1 = *(const f32x4*)(Bcar + cb + 4);
#pragma unroll
        for (int j = 0; j < 4; ++j) {
            h[j] = a0[j] * h[j] + b0[j];
            h[4 + j] = a1[j] * h[4 + j] + b1[j];
        }
    }

    float Dd = rdf(Dvp, d, f);
#pragma unroll 4
    for (int i = 0; i < 32; ++i) {
        int t = t0 + i;
        float de = dlt[i][dl];
        float u = b2f(xc[t * 2048 + d]);
        float dBu = de * u;
        f32x4 Bv0 = *(const f32x4*)&BCs[i][n0];
        f32x4 Bv1 = *(const f32x4*)&BCs[i][n0 + 4];
        f32x4 Cv0 = *(const f32x4*)&BCs[i][16 + n0];
        f32x4 Cv1 = *(const f32x4*)&BCs[i][20 + n0];
        float p = 0.f;
#pragma unroll
        for (int j = 0; j < 8; ++j) {
            float Bv = (j < 4) ? Bv0[j & 3] : Bv1[j & 3];
            float Cv = (j < 4) ? Cv0[j & 3] : Cv1[j & 3];
            float a = __expf(de * A[j]);
            h[j] = a * h[j] + Bv * dBu;
            p += h[j] * Cv;
        }
        p += __shfl_xor(p, 1);  // combine the two n-halves (lanes 2k,2k+1 share d)
        if (nh == 0) {
            float r = b2f(xz[(size_t)t * 4096 + 2048 + d]);
            float yt = p + u * Dd;
            yg[t * 2048 + d] = f2b(yt * r * fsig(r));
        }
    }
}

// ---------------- fallback path (small ws): gemm3 -> delta, then monolithic scan --------------
__global__ __launch_bounds__(256) void gemm3_red_k(const float* __restrict__ parts,
                                                   const u16* __restrict__ Bt,   // W_dt_t [2048,64]
                                                   float* __restrict__ delta,
                                                   const void* __restrict__ bias,
                                                   const int* __restrict__ flag) {
    constexpr int MT = 2, NT = 2, BM = 64, BN = 64, K = 64;
    __shared__ __align__(16) u16 As[2 * BM * 32];
    __shared__ __align__(16) u16 Bs[2 * BN * 32];
    const int tid = threadIdx.x;
    const int w = tid >> 6, lane = tid & 63;
    const int wm = w & 1, wn = w >> 1;
    const int m_blk = blockIdx.x * BM, n_blk = blockIdx.y * BN;
    const int lm = lane & 15, lq = lane >> 4;
    const int sr = lane >> 2, sc = (lane & 3) << 3;
    const int f = flag[0];

    f32x4 acc[MT][NT];
#pragma unroll
    for (int i = 0; i < MT; ++i)
#pragma unroll
        for (int j = 0; j < NT; ++j) acc[i][j] = (f32x4){0.f, 0.f, 0.f, 0.f};

    const int arow = tid >> 2;
    const int acg = (tid & 3) << 3;

#pragma unroll
    for (int cch = 0; cch < 2; ++cch) {
        int row = w * 16;
        gload16(Bt + (size_t)(n_blk + row + sr) * K + cch * 32 + sc, &Bs[cch * BN * 32 + row * 32]);
    }
#pragma unroll
    for (int cch = 0; cch < 2; ++cch) {
        f32x4 s0 = {0.f, 0.f, 0.f, 0.f}, s1 = {0.f, 0.f, 0.f, 0.f};
#pragma unroll
        for (int sl = 0; sl < NSL; ++sl) {
            const float* p = parts + (size_t)sl * 131072 + (size_t)(m_blk + arow) * 128 + cch * 32 + acg;
            s0 += *(const f32x4*)p;
            s1 += *(const f32x4*)(p + 4);
        }
        bf16x8 rv;
#pragma unroll
        for (int j = 0; j < 4; ++j) {
            rv[j] = (short)f2b(s0[j]);
            rv[4 + j] = (short)f2b(s1[j]);
        }
        *(bf16x8*)(&As[cch * BM * 32 + arow * 32 + acg]) = rv;
    }
    __syncthreads();

#pragma unroll
    for (int cch = 0; cch < 2; ++cch) {
        bf16x8 af[MT], bf[NT];
#pragma unroll
        for (int tm = 0; tm < MT; ++tm)
            af[tm] = *(const bf16x8*)(&As[cch * BM * 32 + (wm * 32 + tm * 16 + lm) * 32 + lq * 8]);
#pragma unroll
        for (int tn = 0; tn < NT; ++tn)
            bf[tn] = *(const bf16x8*)(&Bs[cch * BN * 32 + (wn * 32 + tn * 16 + lm) * 32 + lq * 8]);
#pragma unroll
        for (int tm = 0; tm < MT; ++tm)
#pragma unroll
            for (int tn = 0; tn < NT; ++tn)
                acc[tm][tn] = __builtin_amdgcn_mfma_f32_16x16x32_bf16(af[tm], bf[tn],
                                                                      acc[tm][tn], 0, 0, 0);
    }

#pragma unroll
    for (int tm = 0; tm < MT; ++tm)
#pragma unroll
        for (int tn = 0; tn < NT; ++tn)
#pragma unroll
            for (int r = 0; r < 4; ++r) {
                int row = m_blk + wm * 32 + tm * 16 + lq * 4 + r;
                int col = n_blk + wn * 32 + tn * 16 + lm;
                float b = rdf(bias, col, f);
                float t2 = acc[tm][tn][r] + b;
                float sp = fmaxf(t2, 0.f) + __logf(1.f + __expf(-fabsf(t2)));
                delta[(size_t)row * 2048 + col] = sp;
            }
}

__global__ __launch_bounds__(256) void scan_k(const float* __restrict__ delta,
                                              const u16* __restrict__ xc,
                                              const float* __restrict__ parts,
                                              const u16* __restrict__ xz,
                                              const void* __restrict__ A_log,
                                              const void* __restrict__ Dvp,
                                              u16* __restrict__ yg,
                                              const int* __restrict__ flag) {
    int f = *flag;
    int g = blockIdx.x * 256 + threadIdx.x;
    int d = g >> 4, n = g & 15;
    float A = -__expf(rdf(A_log, d * 16 + n, f));
    float Dd = rdf(Dvp, d, f);
    float h = 0.f;
    for (int t = 0; t < LSEQ; ++t) {
        float de = delta[t * 2048 + d];
        float u = b2f(xc[t * 2048 + d]);
        float Bv = 0.f, Cv = 0.f;
#pragma unroll
        for (int sl = 0; sl < NSL; ++sl) {
            Bv += parts[(size_t)sl * 131072 + (size_t)t * 128 + 64 + n];
            Cv += parts[(size_t)sl * 131072 + (size_t)t * 128 + 80 + n];
        }
        h = __expf(de * A) * h + (de * Bv) * u;
        float p = h * Cv;
        p += __shfl_xor(p, 1);
        p += __shfl_xor(p, 2);
        p += __shfl_xor(p, 4);
        p += __shfl_xor(p, 8);
        if (n == 0) {
            float r = b2f(xz[(size_t)t * 4096 + 2048 + d]);
            float yt = p + u * Dd;
            yg[t * 2048 + d] = f2b(yt * r * fsig(r));
        }
    }
}

extern "C" void kernel_launch(void* const* d_in, const int* in_sizes, int n_in,
                              void* d_out, int out_size, void* d_ws, size_t ws_size,
                              hipStream_t stream) {
    const void* x      = d_in[0];
    const void* W_in   = d_in[1];
    const void* conv_w = d_in[2];
    const void* conv_b = d_in[3];
    const void* W_x    = d_in[4];
    const void* W_dt   = d_in[5];
    const void* b_dt   = d_in[6];
    const void* A_log  = d_in[7];
    const void* Dv     = d_in[8];
    const void* W_out  = d_in[9];

    char* ws = (char*)d_ws;
    u16*   xz     = (u16*)(ws);               // [1024,4096] bf16 = 8388608       -> 8388608
    u16*   xconv  = (u16*)(ws + 8388608);     // [1024,2048] bf16 = 4194304       -> 12582912
    float* parts  = (float*)(ws + 12582912);  // [8,1024,128] fp32 = 4194304      -> 16777216
    u16*   W_in_t = (u16*)(ws + 16777216);    // W_in^T [4096,1024] = 8388608     -> 25165824
    u16*   yg     = (u16*)(ws + 25165824);    // [1024,2048] bf16 = 4194304       -> 29360128
    u16*   xb     = (u16*)(ws + 25165824);    // alias yg: x bf16, gemm1 only
    u16*   W_x_t  = (u16*)(ws + 29360128);    // W_x^T padded [128,2048] = 524288 -> 29884416
    u16*   W_dt_t = (u16*)(ws + 29884416);    // W_dt^T [2048,64] = 262144        -> 30146560
    u16*   W_out_t= (u16*)(ws + 30146560);    // W_out^T [1024,2048] = 4194304    -> 34340864
    int*   flag   = (int*)(ws + 34340864);    // 4 B (pad to 34340992)
    float* Acar   = (float*)(ws + 34340992);  // 4194304 -> 38535296
    float* Bcar   = (float*)(ws + 38535296);  // 4194304 -> 42729600
    float* deltag = (float*)(ws + 42729600);  // [1024,2048] fp32 = 8388608 -> 51118208
    float* bcg    = (float*)(ws + 51118208);  // [32,1024] fp32 = 131072 -> 51249280
    float* dfb    = (float*)(ws + 34340992);  // fallback delta alias (Acar+Bcar region)
    const bool chunked_ok = (ws_size >= 51249280);

    // 0) prep: detect + x->bf16 + W_in^T only (other transposes ride gemm1)
    prep_k<<<5120, 256, 0, stream>>>(x, W_in, xb, W_in_t, flag);
    // 1) gemm1 FAT: xz = xb @ W_in^T (512 gemm blocks = 2/CU) + 2432 transpose riders
    gemm1_fat_k<<<dim3(16, 184), 256, 0, stream>>>(xb, W_in_t, xz,
                                                   W_out, W_x, W_dt,
                                                   W_out_t, W_x_t, W_dt_t, flag);
    // 2+3) x_dbl partials = silu(conv(x_in)) @ W_x^T; BM=32 x BN=64 (n-split), 8 k-slices ->
    //      512 blocks = 2/CU (R15 was 256 = 1/CU); NSL stays 8 (scan1 untouched); conv
    //      duplicated across n-halves (~1.2us) for cross-block TLP on the barrier drains
    gemm2_conv_k<<<dim3(32, 2, 8), 256, 0, stream>>>(xz, W_x_t, parts, xconv,
                                                     conv_w, conv_b, flag);

    // 4+5) scan: 2 dispatches. scan1 computes delta in-block + persists dlt/BC sums;
    //      scan3 reloads them and inlines the lookback (dispatch boundary = the sync).
    if (chunked_ok) {
        scan1_k<<<512, 256, 0, stream>>>(xconv, parts, W_dt_t, b_dt, A_log, Acar, Bcar,
                                         deltag, bcg, flag);
        scan3_k<<<512, 256, 0, stream>>>(xconv, deltag, bcg, xz, A_log, Dv,
                                         Acar, Bcar, yg, flag);
    } else {
        gemm3_red_k<<<dim3(16, 32), 256, 0, stream>>>(parts, W_dt_t, dfb, b_dt, flag);
        scan_k<<<128, 256, 0, stream>>>(dfb, xconv, parts, xz, A_log, Dv, yg, flag);
    }

    // 6) out = yg @ W_out  [1024,1024]  (64x64 tiles, 256 blocks; R13 config — <1,2> falsified)
    gemm_bt<2, 2, 2><<<dim3(16, 16), 256, 0, stream>>>(yg, W_out_t, d_out,
                                                       1024, 1024, 2048, flag);
}